// Round 2
// baseline (3751.003 us; speedup 1.0000x reference)
//
#include <hip/hip_runtime.h>

#define LN_EPS 1e-5f
#define KPAD 288   // 272 real k's padded with zeros to 8 chunks of 36
#define KC 36
#define NCHUNK 8

// ---- build transposed weights WT[j][KPAD]: k<128 -> Ws[k][j]; 128<=k<272 -> Wm[k-128][j]; else 0
__global__ __launch_bounds__(256) void build_wt(
    const float* __restrict__ Ws, const float* __restrict__ Wm,
    float* __restrict__ WT, int J) {
  int idx = blockIdx.x * 256 + threadIdx.x;
  if (idx >= J * KPAD) return;
  int j = idx / KPAD, k = idx - j * KPAD;
  float v = 0.f;
  if (k < 128) v = Ws[k * J + j];
  else if (k < 272) v = Wm[(k - 128) * J + j];
  WT[idx] = v;
}

// ---- scatter: S[tgt] += feat[src], feat is [N,128]; 32 threads/edge, float4 ----
__global__ __launch_bounds__(256) void scatter_feat128(
    const float* __restrict__ feat,
    const int* __restrict__ src,
    const int* __restrict__ tgt,
    float* __restrict__ S, int E) {
  int lane = threadIdx.x & 31;
  int esub = threadIdx.x >> 5;
  for (int e0 = blockIdx.x * 8; e0 < E; e0 += gridDim.x * 8) {
    int e = e0 + esub;
    if (e < E) {
      int s = src[e], t = tgt[e];
      float4 v = *(const float4*)&feat[(size_t)s * 128 + lane * 4];
      float* dst = &S[(size_t)t * 128 + lane * 4];
      atomicAdd(dst + 0, v.x);
      atomicAdd(dst + 1, v.y);
      atomicAdd(dst + 2, v.z);
      atomicAdd(dst + 3, v.w);
    }
  }
}

// ---- scatter: SE[tgt] += ef[e] (16 wide), deg[tgt] += 1 ----
__global__ __launch_bounds__(256) void scatter_edge(
    const float* __restrict__ ef,
    const int* __restrict__ tgt,
    float* __restrict__ SE, float* __restrict__ deg, int E) {
  int e = blockIdx.x * 16 + (threadIdx.x >> 4);
  if (e >= E) return;
  int f = threadIdx.x & 15;
  int t = tgt[e];
  atomicAdd(&SE[t * 16 + f], ef[e * 16 + f]);
  if (f == 0) atomicAdd(&deg[t], 1.0f);
}

// ---- layer 0 GEMM: [32 nodes x 272] @ [272 x 128] + bias + LN + ReLU ----
// 256 threads: tn=tid>>5 (8 groups x 4 nodes), tj=tid&31 (32 groups x 4 feats)
__global__ __launch_bounds__(256) void layer0_gemm(
    const float* __restrict__ x, const float* __restrict__ SX,
    const float* __restrict__ SE, const float* __restrict__ deg,
    const float* __restrict__ WT, const float* __restrict__ bs,
    const float* __restrict__ bm, const float* __restrict__ gam,
    const float* __restrict__ bet, float* __restrict__ h, int N) {
  __shared__ float u[32][KPAD];     // 36864 B
  __shared__ float wl[128][KC];     // 18432 B
  __shared__ float dgs[32], dinv[32];
  int tid = threadIdx.x;
  int n0 = blockIdx.x * 32;
  if (tid < 32) {
    int n = n0 + tid;
    float dg = (n < N) ? deg[n] : 0.f;
    dgs[tid] = dg;
    dinv[tid] = dg > 0.f ? 1.f / dg : 0.f;
  }
  __syncthreads();
  for (int idx = tid; idx < 32 * 128; idx += 256) {
    int m = idx >> 7, f = idx & 127;
    int n = n0 + m;
    if (n < N) {
      u[m][f]       = x[(size_t)n * 128 + f];
      u[m][128 + f] = SX[(size_t)n * 128 + f] * dinv[m];
    } else { u[m][f] = 0.f; u[m][128 + f] = 0.f; }
  }
  for (int idx = tid; idx < 32 * 32; idx += 256) {
    int m = idx >> 5, f = idx & 31;
    int n = n0 + m;
    u[m][256 + f] = (f < 16 && n < N) ? SE[(size_t)n * 16 + f] * dinv[m] : 0.f;
  }

  int tn = tid >> 5, tj = tid & 31;
  int jb = tj * 4;
  float acc[4][4];
  #pragma unroll
  for (int m = 0; m < 4; ++m) {
    bool has = dgs[tn * 4 + m] > 0.f;
    #pragma unroll
    for (int q = 0; q < 4; ++q)
      acc[m][q] = bs[jb + q] + (has ? bm[jb + q] : 0.f);
  }

  for (int c = 0; c < NCHUNK; ++c) {
    if (c) __syncthreads();
    for (int idx = tid; idx < 128 * KC; idx += 256) {
      int j = idx / KC, kk = idx - j * KC;
      wl[j][kk] = WT[(size_t)j * KPAD + c * KC + kk];
    }
    __syncthreads();
    #pragma unroll 3
    for (int kk = 0; kk < KC; kk += 4) {
      float4 uv[4], wv[4];
      #pragma unroll
      for (int m = 0; m < 4; ++m) uv[m] = *(const float4*)&u[tn * 4 + m][c * KC + kk];
      #pragma unroll
      for (int q = 0; q < 4; ++q) wv[q] = *(const float4*)&wl[jb + q][kk];
      #pragma unroll
      for (int m = 0; m < 4; ++m) {
        #pragma unroll
        for (int q = 0; q < 4; ++q) {
          acc[m][q] = fmaf(uv[m].x, wv[q].x, acc[m][q]);
          acc[m][q] = fmaf(uv[m].y, wv[q].y, acc[m][q]);
          acc[m][q] = fmaf(uv[m].z, wv[q].z, acc[m][q]);
          acc[m][q] = fmaf(uv[m].w, wv[q].w, acc[m][q]);
        }
      }
    }
  }

  __syncthreads();
  #pragma unroll
  for (int m = 0; m < 4; ++m)
    *(float4*)&u[tn * 4 + m][jb] = make_float4(acc[m][0], acc[m][1], acc[m][2], acc[m][3]);
  __syncthreads();

  // LN + ReLU: 8 threads per node, 16 feats each
  int node = tid >> 3, s = tid & 7;
  int fb = s * 16;
  float4 v0 = *(const float4*)&u[node][fb];
  float4 v1 = *(const float4*)&u[node][fb + 4];
  float4 v2 = *(const float4*)&u[node][fb + 8];
  float4 v3 = *(const float4*)&u[node][fb + 12];
  float sum = v0.x + v0.y + v0.z + v0.w + v1.x + v1.y + v1.z + v1.w
            + v2.x + v2.y + v2.z + v2.w + v3.x + v3.y + v3.z + v3.w;
  float sq  = v0.x*v0.x + v0.y*v0.y + v0.z*v0.z + v0.w*v0.w
            + v1.x*v1.x + v1.y*v1.y + v1.z*v1.z + v1.w*v1.w
            + v2.x*v2.x + v2.y*v2.y + v2.z*v2.z + v2.w*v2.w
            + v3.x*v3.x + v3.y*v3.y + v3.z*v3.z + v3.w*v3.w;
  #pragma unroll
  for (int off = 1; off < 8; off <<= 1) {
    sum += __shfl_xor(sum, off);
    sq  += __shfl_xor(sq, off);
  }
  float mean = sum * (1.f / 128.f);
  float var  = sq * (1.f / 128.f) - mean * mean;
  float rstd = rsqrtf(var + LN_EPS);
  int n = n0 + node;
  if (n < N) {
    float4 ga0 = *(const float4*)&gam[fb],     ga1 = *(const float4*)&gam[fb + 4];
    float4 ga2 = *(const float4*)&gam[fb + 8], ga3 = *(const float4*)&gam[fb + 12];
    float4 be0 = *(const float4*)&bet[fb],     be1 = *(const float4*)&bet[fb + 4];
    float4 be2 = *(const float4*)&bet[fb + 8], be3 = *(const float4*)&bet[fb + 12];
    float* hp = &h[(size_t)n * 128 + fb];
    float4 o;
    o.x = fmaxf((v0.x - mean) * rstd * ga0.x + be0.x, 0.f);
    o.y = fmaxf((v0.y - mean) * rstd * ga0.y + be0.y, 0.f);
    o.z = fmaxf((v0.z - mean) * rstd * ga0.z + be0.z, 0.f);
    o.w = fmaxf((v0.w - mean) * rstd * ga0.w + be0.w, 0.f);
    *(float4*)(hp + 0) = o;
    o.x = fmaxf((v1.x - mean) * rstd * ga1.x + be1.x, 0.f);
    o.y = fmaxf((v1.y - mean) * rstd * ga1.y + be1.y, 0.f);
    o.z = fmaxf((v1.z - mean) * rstd * ga1.z + be1.z, 0.f);
    o.w = fmaxf((v1.w - mean) * rstd * ga1.w + be1.w, 0.f);
    *(float4*)(hp + 4) = o;
    o.x = fmaxf((v2.x - mean) * rstd * ga2.x + be2.x, 0.f);
    o.y = fmaxf((v2.y - mean) * rstd * ga2.y + be2.y, 0.f);
    o.z = fmaxf((v2.z - mean) * rstd * ga2.z + be2.z, 0.f);
    o.w = fmaxf((v2.w - mean) * rstd * ga2.w + be2.w, 0.f);
    *(float4*)(hp + 8) = o;
    o.x = fmaxf((v3.x - mean) * rstd * ga3.x + be3.x, 0.f);
    o.y = fmaxf((v3.y - mean) * rstd * ga3.y + be3.y, 0.f);
    o.z = fmaxf((v3.z - mean) * rstd * ga3.z + be3.z, 0.f);
    o.w = fmaxf((v3.w - mean) * rstd * ga3.w + be3.w, 0.f);
    *(float4*)(hp + 12) = o;
  }
}

// ---- layer 1 GEMM: [32 nodes x 272] @ [272 x 64] + bias + LN + fused pooling ----
// 256 threads: tn=tid>>5 (8 x 4 nodes), tj=tid&31 (32 x 2 feats)
__global__ __launch_bounds__(256) void layer1_gemm(
    const float* __restrict__ hin, const float* __restrict__ SH,
    const float* __restrict__ SE, const float* __restrict__ deg,
    const float* __restrict__ WT, const float* __restrict__ bs,
    const float* __restrict__ bm, const float* __restrict__ gam,
    const float* __restrict__ bet, const int* __restrict__ batch,
    float* __restrict__ node_emb, float* __restrict__ pooled,
    float* __restrict__ counts, int N) {
  __shared__ float u[32][KPAD];   // 36864 B
  __shared__ float wl[64][KC];    // 9216 B
  __shared__ float dgs[32], dinv[32];
  int tid = threadIdx.x;
  int n0 = blockIdx.x * 32;
  if (tid < 32) {
    int n = n0 + tid;
    float dg = (n < N) ? deg[n] : 0.f;
    dgs[tid] = dg;
    dinv[tid] = dg > 0.f ? 1.f / dg : 0.f;
  }
  __syncthreads();
  for (int idx = tid; idx < 32 * 128; idx += 256) {
    int m = idx >> 7, f = idx & 127;
    int n = n0 + m;
    if (n < N) {
      u[m][f]       = hin[(size_t)n * 128 + f];
      u[m][128 + f] = SH[(size_t)n * 128 + f] * dinv[m];
    } else { u[m][f] = 0.f; u[m][128 + f] = 0.f; }
  }
  for (int idx = tid; idx < 32 * 32; idx += 256) {
    int m = idx >> 5, f = idx & 31;
    int n = n0 + m;
    u[m][256 + f] = (f < 16 && n < N) ? SE[(size_t)n * 16 + f] * dinv[m] : 0.f;
  }

  int tn = tid >> 5, tj = tid & 31;
  int jb = tj * 2;
  float acc[4][2];
  #pragma unroll
  for (int m = 0; m < 4; ++m) {
    bool has = dgs[tn * 4 + m] > 0.f;
    #pragma unroll
    for (int q = 0; q < 2; ++q)
      acc[m][q] = bs[jb + q] + (has ? bm[jb + q] : 0.f);
  }

  for (int c = 0; c < NCHUNK; ++c) {
    if (c) __syncthreads();
    for (int idx = tid; idx < 64 * KC; idx += 256) {
      int j = idx / KC, kk = idx - j * KC;
      wl[j][kk] = WT[(size_t)j * KPAD + c * KC + kk];
    }
    __syncthreads();
    #pragma unroll 3
    for (int kk = 0; kk < KC; kk += 4) {
      float4 uv[4], wv[2];
      #pragma unroll
      for (int m = 0; m < 4; ++m) uv[m] = *(const float4*)&u[tn * 4 + m][c * KC + kk];
      #pragma unroll
      for (int q = 0; q < 2; ++q) wv[q] = *(const float4*)&wl[jb + q][kk];
      #pragma unroll
      for (int m = 0; m < 4; ++m) {
        #pragma unroll
        for (int q = 0; q < 2; ++q) {
          acc[m][q] = fmaf(uv[m].x, wv[q].x, acc[m][q]);
          acc[m][q] = fmaf(uv[m].y, wv[q].y, acc[m][q]);
          acc[m][q] = fmaf(uv[m].z, wv[q].z, acc[m][q]);
          acc[m][q] = fmaf(uv[m].w, wv[q].w, acc[m][q]);
        }
      }
    }
  }

  __syncthreads();
  #pragma unroll
  for (int m = 0; m < 4; ++m)
    *(float2*)&u[tn * 4 + m][jb] = make_float2(acc[m][0], acc[m][1]);
  __syncthreads();

  // LN: 8 threads per node, 8 feats each
  int node = tid >> 3, s = tid & 7;
  int fb = s * 8;
  float4 v0 = *(const float4*)&u[node][fb];
  float4 v1 = *(const float4*)&u[node][fb + 4];
  float sum = v0.x + v0.y + v0.z + v0.w + v1.x + v1.y + v1.z + v1.w;
  float sq  = v0.x*v0.x + v0.y*v0.y + v0.z*v0.z + v0.w*v0.w
            + v1.x*v1.x + v1.y*v1.y + v1.z*v1.z + v1.w*v1.w;
  #pragma unroll
  for (int off = 1; off < 8; off <<= 1) {
    sum += __shfl_xor(sum, off);
    sq  += __shfl_xor(sq, off);
  }
  float mean = sum * (1.f / 64.f);
  float var  = sq * (1.f / 64.f) - mean * mean;
  float rstd = rsqrtf(var + LN_EPS);
  int n = n0 + node;
  if (n < N) {
    float4 ga0 = *(const float4*)&gam[fb], ga1 = *(const float4*)&gam[fb + 4];
    float4 be0 = *(const float4*)&bet[fb], be1 = *(const float4*)&bet[fb + 4];
    float4 o0, o1;
    o0.x = (v0.x - mean) * rstd * ga0.x + be0.x;
    o0.y = (v0.y - mean) * rstd * ga0.y + be0.y;
    o0.z = (v0.z - mean) * rstd * ga0.z + be0.z;
    o0.w = (v0.w - mean) * rstd * ga0.w + be0.w;
    o1.x = (v1.x - mean) * rstd * ga1.x + be1.x;
    o1.y = (v1.y - mean) * rstd * ga1.y + be1.y;
    o1.z = (v1.z - mean) * rstd * ga1.z + be1.z;
    o1.w = (v1.w - mean) * rstd * ga1.w + be1.w;
    float* op = &node_emb[(size_t)n * 64 + fb];
    *(float4*)(op + 0) = o0;
    *(float4*)(op + 4) = o1;
    int grp = batch[n];
    float* pp = &pooled[grp * 64 + fb];
    atomicAdd(pp + 0, o0.x); atomicAdd(pp + 1, o0.y);
    atomicAdd(pp + 2, o0.z); atomicAdd(pp + 3, o0.w);
    atomicAdd(pp + 4, o1.x); atomicAdd(pp + 5, o1.y);
    atomicAdd(pp + 6, o1.z); atomicAdd(pp + 7, o1.w);
    if (s == 0) atomicAdd(&counts[grp], 1.0f);
  }
}

__global__ __launch_bounds__(64) void graph_mean(
    const float* __restrict__ pooled, const float* __restrict__ counts,
    float* __restrict__ out) {
  int g = blockIdx.x, j = threadIdx.x;
  float inv = 1.f / fmaxf(counts[g], 1.f);
  out[g * 64 + j] = pooled[g * 64 + j] * inv;
}

extern "C" void kernel_launch(void* const* d_in, const int* in_sizes, int n_in,
                              void* d_out, int out_size, void* d_ws, size_t ws_size,
                              hipStream_t stream) {
  const float* x   = (const float*)d_in[0];
  const float* ef  = (const float*)d_in[1];
  const float* Ws0 = (const float*)d_in[2];
  const float* bs0 = (const float*)d_in[3];
  const float* Wm0 = (const float*)d_in[4];
  const float* bm0 = (const float*)d_in[5];
  const float* g0  = (const float*)d_in[6];
  const float* be0 = (const float*)d_in[7];
  const float* Ws1 = (const float*)d_in[8];
  const float* bs1 = (const float*)d_in[9];
  const float* Wm1 = (const float*)d_in[10];
  const float* bm1 = (const float*)d_in[11];
  const float* g1  = (const float*)d_in[12];
  const float* be1 = (const float*)d_in[13];
  const int* edge_index = (const int*)d_in[14];
  const int* batch = (const int*)d_in[15];

  const int N = in_sizes[0] / 128;
  const int E = in_sizes[14] / 2;
  const int G = 64;
  const int* src = edge_index;
  const int* tgt = edge_index + E;

  char* ws = (char*)d_ws;
  size_t off = 0;
  auto alloc = [&](size_t bytes) -> void* {
    void* p = ws + off;
    off = (off + bytes + 255) & ~(size_t)255;
    return p;
  };
  float* SX     = (float*)alloc((size_t)N * 128 * 4);  // reused as SH after layer 0
  float* SE     = (float*)alloc((size_t)N * 16 * 4);
  float* deg    = (float*)alloc((size_t)N * 4);
  float* h      = (float*)alloc((size_t)N * 128 * 4);
  float* WT0    = (float*)alloc((size_t)128 * KPAD * 4);
  float* WT1    = (float*)alloc((size_t)64 * KPAD * 4);
  float* pooled = (float*)alloc((size_t)G * 64 * 4);
  float* counts = (float*)alloc((size_t)G * 4);

  hipMemsetAsync(SX, 0, (size_t)N * 128 * 4, stream);
  hipMemsetAsync(SE, 0, (size_t)N * 16 * 4, stream);
  hipMemsetAsync(deg, 0, (size_t)N * 4, stream);
  hipMemsetAsync(pooled, 0, (size_t)G * 64 * 4, stream);
  hipMemsetAsync(counts, 0, (size_t)G * 4, stream);

  build_wt<<<(128 * KPAD + 255) / 256, 256, 0, stream>>>(Ws0, Wm0, WT0, 128);
  build_wt<<<(64 * KPAD + 255) / 256, 256, 0, stream>>>(Ws1, Wm1, WT1, 64);

  scatter_edge<<<(E + 15) / 16, 256, 0, stream>>>(ef, tgt, SE, deg, E);
  scatter_feat128<<<8192, 256, 0, stream>>>(x, src, tgt, SX, E);

  layer0_gemm<<<(N + 31) / 32, 256, 0, stream>>>(
      x, SX, SE, deg, WT0, bs0, bm0, g0, be0, h, N);

  hipMemsetAsync(SX, 0, (size_t)N * 128 * 4, stream);
  scatter_feat128<<<8192, 256, 0, stream>>>(h, src, tgt, SX, E);

  layer1_gemm<<<(N + 31) / 32, 256, 0, stream>>>(
      h, SX, SE, deg, WT1, bs1, bm1, g1, be1, batch,
      (float*)d_out, pooled, counts, N);

  graph_mean<<<G, 64, 0, stream>>>(pooled, counts, (float*)d_out + (size_t)N * 64);
}

// Round 3
// 1464.280 us; speedup vs baseline: 2.5617x; 2.5617x over previous
//
#include <hip/hip_runtime.h>

#define LN_EPS 1e-5f
#define KPAD 288   // 272 real k's padded with zeros to 8 chunks of 36
#define KC 36
#define NCHUNK 8
#define UPAD 292   // u row stride (floats), breaks LN-phase bank alignment

// ---- CSR build: histogram of tgt ----
__global__ __launch_bounds__(256) void hist_tgt(
    const int* __restrict__ tgt, int* __restrict__ cnt, int E) {
  int e = blockIdx.x * 256 + threadIdx.x;
  if (e < E) atomicAdd(&cnt[tgt[e]], 1);
}

// ---- CSR build: exclusive scan over cnt -> rowptr (single block) ----
__global__ __launch_bounds__(1024) void scan_rowptr(
    const int* __restrict__ cnt, int* __restrict__ rowptr, int N) {
  __shared__ int part[1024];
  int tid = threadIdx.x;
  int per = (N + 1023) / 1024;
  int start = tid * per;
  int end = min(start + per, N);
  int s = 0;
  for (int i = start; i < end; ++i) s += cnt[i];
  part[tid] = s;
  __syncthreads();
  for (int off = 1; off < 1024; off <<= 1) {
    int v = (tid >= off) ? part[tid - off] : 0;
    __syncthreads();
    part[tid] += v;
    __syncthreads();
  }
  int excl = (tid == 0) ? 0 : part[tid - 1];
  for (int i = start; i < end; ++i) {
    rowptr[i] = excl;
    excl += cnt[i];
  }
  if (tid == 1023) rowptr[N] = excl;
}

// ---- CSR build: fill (src, eid) pairs ----
__global__ __launch_bounds__(256) void fill_csr(
    const int* __restrict__ src, const int* __restrict__ tgt,
    const int* __restrict__ rowptr, int* __restrict__ cur,
    int2* __restrict__ csr, int E) {
  int e = blockIdx.x * 256 + threadIdx.x;
  if (e >= E) return;
  int t = tgt[e];
  int pos = atomicAdd(&cur[t], 1);
  csr[rowptr[t] + pos] = make_int2(src[e], e);
}

// ---- gather-aggregate for layer 0: SX[n]=sum x[src], SE[n]=sum ef[eid], degF ----
__global__ __launch_bounds__(256) void agg0(
    const float* __restrict__ x, const float* __restrict__ ef,
    const int* __restrict__ rowptr, const int2* __restrict__ csr,
    float* __restrict__ SX, float* __restrict__ SE,
    float* __restrict__ degF, int N) {
  int f = threadIdx.x & 127;
  int n = blockIdx.x * 2 + (threadIdx.x >> 7);
  if (n >= N) return;
  int b = rowptr[n], d = rowptr[n + 1] - b;
  float acc = 0.f, acce = 0.f;
  for (int i = 0; i < d; ++i) {
    int2 p = csr[b + i];
    acc += x[(size_t)p.x * 128 + f];
    if (f < 16) acce += ef[(size_t)p.y * 16 + f];
  }
  SX[(size_t)n * 128 + f] = acc;
  if (f < 16) SE[(size_t)n * 16 + f] = acce;
  if (f == 0) degF[n] = (float)d;
}

// ---- gather-aggregate for layer 1: SH[n]=sum h[src] ----
__global__ __launch_bounds__(256) void agg1(
    const float* __restrict__ h, const int* __restrict__ rowptr,
    const int2* __restrict__ csr, float* __restrict__ SH, int N) {
  int f = threadIdx.x & 127;
  int n = blockIdx.x * 2 + (threadIdx.x >> 7);
  if (n >= N) return;
  int b = rowptr[n], d = rowptr[n + 1] - b;
  float acc = 0.f;
  for (int i = 0; i < d; ++i) {
    int2 p = csr[b + i];
    acc += h[(size_t)p.x * 128 + f];
  }
  SH[(size_t)n * 128 + f] = acc;
}

// ---- layer 0 GEMM: [32 nodes x 272] @ [272 x 128] + bias + LN + ReLU ----
// 256 threads: tn=tid>>5 (8 groups x 4 nodes), tj=tid&31 (32 groups x 4 feats)
__global__ __launch_bounds__(256) void layer0_gemm(
    const float* __restrict__ x, const float* __restrict__ SX,
    const float* __restrict__ SE, const float* __restrict__ deg,
    const float* __restrict__ Ws, const float* __restrict__ Wm,
    const float* __restrict__ bs, const float* __restrict__ bm,
    const float* __restrict__ gam, const float* __restrict__ bet,
    float* __restrict__ h, int N) {
  __shared__ float u[32][UPAD];
  __shared__ float wl[KC][128];
  __shared__ float dgs[32], dinv[32];
  int tid = threadIdx.x;
  int n0 = blockIdx.x * 32;
  if (tid < 32) {
    int n = n0 + tid;
    float dg = (n < N) ? deg[n] : 0.f;
    dgs[tid] = dg;
    dinv[tid] = dg > 0.f ? 1.f / dg : 0.f;
  }
  __syncthreads();
  for (int idx = tid; idx < 32 * 128; idx += 256) {
    int m = idx >> 7, f = idx & 127;
    int n = n0 + m;
    if (n < N) {
      u[m][f]       = x[(size_t)n * 128 + f];
      u[m][128 + f] = SX[(size_t)n * 128 + f] * dinv[m];
    } else { u[m][f] = 0.f; u[m][128 + f] = 0.f; }
  }
  for (int idx = tid; idx < 32 * 32; idx += 256) {
    int m = idx >> 5, f = idx & 31;
    int n = n0 + m;
    u[m][256 + f] = (f < 16 && n < N) ? SE[(size_t)n * 16 + f] * dinv[m] : 0.f;
  }

  int tn = tid >> 5, tj = tid & 31;
  int jb = tj * 4;
  float acc[4][4];
  #pragma unroll
  for (int m = 0; m < 4; ++m) {
    bool has = dgs[tn * 4 + m] > 0.f;
    #pragma unroll
    for (int q = 0; q < 4; ++q)
      acc[m][q] = bs[jb + q] + (has ? bm[jb + q] : 0.f);
  }

  for (int c = 0; c < NCHUNK; ++c) {
    if (c) __syncthreads();
    for (int idx = tid; idx < KC * 128; idx += 256) {
      int kk = idx >> 7, j = idx & 127;
      int k = c * KC + kk;
      float v = 0.f;
      if (k < 128) v = Ws[k * 128 + j];
      else if (k < 272) v = Wm[(k - 128) * 128 + j];
      wl[kk][j] = v;
    }
    __syncthreads();
    #pragma unroll 3
    for (int kk = 0; kk < KC; kk += 4) {
      float4 uv[4], wv[4];
      #pragma unroll
      for (int m = 0; m < 4; ++m) uv[m] = *(const float4*)&u[tn * 4 + m][c * KC + kk];
      #pragma unroll
      for (int t = 0; t < 4; ++t) wv[t] = *(const float4*)&wl[kk + t][jb];
      #pragma unroll
      for (int m = 0; m < 4; ++m) {
        float us[4] = {uv[m].x, uv[m].y, uv[m].z, uv[m].w};
        #pragma unroll
        for (int t = 0; t < 4; ++t) {
          acc[m][0] = fmaf(us[t], wv[t].x, acc[m][0]);
          acc[m][1] = fmaf(us[t], wv[t].y, acc[m][1]);
          acc[m][2] = fmaf(us[t], wv[t].z, acc[m][2]);
          acc[m][3] = fmaf(us[t], wv[t].w, acc[m][3]);
        }
      }
    }
  }

  __syncthreads();
  #pragma unroll
  for (int m = 0; m < 4; ++m)
    *(float4*)&u[tn * 4 + m][jb] = make_float4(acc[m][0], acc[m][1], acc[m][2], acc[m][3]);
  __syncthreads();

  // LN + ReLU: 8 threads per node, 16 feats each
  int node = tid >> 3, s = tid & 7;
  int fb = s * 16;
  float4 v0 = *(const float4*)&u[node][fb];
  float4 v1 = *(const float4*)&u[node][fb + 4];
  float4 v2 = *(const float4*)&u[node][fb + 8];
  float4 v3 = *(const float4*)&u[node][fb + 12];
  float sum = v0.x + v0.y + v0.z + v0.w + v1.x + v1.y + v1.z + v1.w
            + v2.x + v2.y + v2.z + v2.w + v3.x + v3.y + v3.z + v3.w;
  float sq  = v0.x*v0.x + v0.y*v0.y + v0.z*v0.z + v0.w*v0.w
            + v1.x*v1.x + v1.y*v1.y + v1.z*v1.z + v1.w*v1.w
            + v2.x*v2.x + v2.y*v2.y + v2.z*v2.z + v2.w*v2.w
            + v3.x*v3.x + v3.y*v3.y + v3.z*v3.z + v3.w*v3.w;
  #pragma unroll
  for (int off = 1; off < 8; off <<= 1) {
    sum += __shfl_xor(sum, off);
    sq  += __shfl_xor(sq, off);
  }
  float mean = sum * (1.f / 128.f);
  float var  = sq * (1.f / 128.f) - mean * mean;
  float rstd = rsqrtf(var + LN_EPS);
  int n = n0 + node;
  if (n < N) {
    float4 ga0 = *(const float4*)&gam[fb],     ga1 = *(const float4*)&gam[fb + 4];
    float4 ga2 = *(const float4*)&gam[fb + 8], ga3 = *(const float4*)&gam[fb + 12];
    float4 be0 = *(const float4*)&bet[fb],     be1 = *(const float4*)&bet[fb + 4];
    float4 be2 = *(const float4*)&bet[fb + 8], be3 = *(const float4*)&bet[fb + 12];
    float* hp = &h[(size_t)n * 128 + fb];
    float4 o;
    o.x = fmaxf((v0.x - mean) * rstd * ga0.x + be0.x, 0.f);
    o.y = fmaxf((v0.y - mean) * rstd * ga0.y + be0.y, 0.f);
    o.z = fmaxf((v0.z - mean) * rstd * ga0.z + be0.z, 0.f);
    o.w = fmaxf((v0.w - mean) * rstd * ga0.w + be0.w, 0.f);
    *(float4*)(hp + 0) = o;
    o.x = fmaxf((v1.x - mean) * rstd * ga1.x + be1.x, 0.f);
    o.y = fmaxf((v1.y - mean) * rstd * ga1.y + be1.y, 0.f);
    o.z = fmaxf((v1.z - mean) * rstd * ga1.z + be1.z, 0.f);
    o.w = fmaxf((v1.w - mean) * rstd * ga1.w + be1.w, 0.f);
    *(float4*)(hp + 4) = o;
    o.x = fmaxf((v2.x - mean) * rstd * ga2.x + be2.x, 0.f);
    o.y = fmaxf((v2.y - mean) * rstd * ga2.y + be2.y, 0.f);
    o.z = fmaxf((v2.z - mean) * rstd * ga2.z + be2.z, 0.f);
    o.w = fmaxf((v2.w - mean) * rstd * ga2.w + be2.w, 0.f);
    *(float4*)(hp + 8) = o;
    o.x = fmaxf((v3.x - mean) * rstd * ga3.x + be3.x, 0.f);
    o.y = fmaxf((v3.y - mean) * rstd * ga3.y + be3.y, 0.f);
    o.z = fmaxf((v3.z - mean) * rstd * ga3.z + be3.z, 0.f);
    o.w = fmaxf((v3.w - mean) * rstd * ga3.w + be3.w, 0.f);
    *(float4*)(hp + 12) = o;
  }
}

// ---- layer 1 GEMM: [32 nodes x 272] @ [272 x 64] + bias + LN + fused pooling ----
// 256 threads: tn=tid>>5 (8 x 4 nodes), tj=tid&31 (32 x 2 feats)
__global__ __launch_bounds__(256) void layer1_gemm(
    const float* __restrict__ hin, const float* __restrict__ SH,
    const float* __restrict__ SE, const float* __restrict__ deg,
    const float* __restrict__ Ws, const float* __restrict__ Wm,
    const float* __restrict__ bs, const float* __restrict__ bm,
    const float* __restrict__ gam, const float* __restrict__ bet,
    const int* __restrict__ batch,
    float* __restrict__ node_emb, float* __restrict__ pooled,
    float* __restrict__ counts, int N) {
  __shared__ float u[32][UPAD];
  __shared__ float wl[KC][64];
  __shared__ float dgs[32], dinv[32];
  int tid = threadIdx.x;
  int n0 = blockIdx.x * 32;
  if (tid < 32) {
    int n = n0 + tid;
    float dg = (n < N) ? deg[n] : 0.f;
    dgs[tid] = dg;
    dinv[tid] = dg > 0.f ? 1.f / dg : 0.f;
  }
  __syncthreads();
  for (int idx = tid; idx < 32 * 128; idx += 256) {
    int m = idx >> 7, f = idx & 127;
    int n = n0 + m;
    if (n < N) {
      u[m][f]       = hin[(size_t)n * 128 + f];
      u[m][128 + f] = SH[(size_t)n * 128 + f] * dinv[m];
    } else { u[m][f] = 0.f; u[m][128 + f] = 0.f; }
  }
  for (int idx = tid; idx < 32 * 32; idx += 256) {
    int m = idx >> 5, f = idx & 31;
    int n = n0 + m;
    u[m][256 + f] = (f < 16 && n < N) ? SE[(size_t)n * 16 + f] * dinv[m] : 0.f;
  }

  int tn = tid >> 5, tj = tid & 31;
  int jb = tj * 2;
  float acc[4][2];
  #pragma unroll
  for (int m = 0; m < 4; ++m) {
    bool has = dgs[tn * 4 + m] > 0.f;
    #pragma unroll
    for (int q = 0; q < 2; ++q)
      acc[m][q] = bs[jb + q] + (has ? bm[jb + q] : 0.f);
  }

  for (int c = 0; c < NCHUNK; ++c) {
    if (c) __syncthreads();
    for (int idx = tid; idx < KC * 64; idx += 256) {
      int kk = idx >> 6, j = idx & 63;
      int k = c * KC + kk;
      float v = 0.f;
      if (k < 128) v = Ws[k * 64 + j];
      else if (k < 272) v = Wm[(k - 128) * 64 + j];
      wl[kk][j] = v;
    }
    __syncthreads();
    #pragma unroll 3
    for (int kk = 0; kk < KC; kk += 4) {
      float4 uv[4];
      float2 wv[4];
      #pragma unroll
      for (int m = 0; m < 4; ++m) uv[m] = *(const float4*)&u[tn * 4 + m][c * KC + kk];
      #pragma unroll
      for (int t = 0; t < 4; ++t) wv[t] = *(const float2*)&wl[kk + t][jb];
      #pragma unroll
      for (int m = 0; m < 4; ++m) {
        float us[4] = {uv[m].x, uv[m].y, uv[m].z, uv[m].w};
        #pragma unroll
        for (int t = 0; t < 4; ++t) {
          acc[m][0] = fmaf(us[t], wv[t].x, acc[m][0]);
          acc[m][1] = fmaf(us[t], wv[t].y, acc[m][1]);
        }
      }
    }
  }

  __syncthreads();
  #pragma unroll
  for (int m = 0; m < 4; ++m)
    *(float2*)&u[tn * 4 + m][jb] = make_float2(acc[m][0], acc[m][1]);
  __syncthreads();

  // LN: 8 threads per node, 8 feats each
  int node = tid >> 3, s = tid & 7;
  int fb = s * 8;
  float4 v0 = *(const float4*)&u[node][fb];
  float4 v1 = *(const float4*)&u[node][fb + 4];
  float sum = v0.x + v0.y + v0.z + v0.w + v1.x + v1.y + v1.z + v1.w;
  float sq  = v0.x*v0.x + v0.y*v0.y + v0.z*v0.z + v0.w*v0.w
            + v1.x*v1.x + v1.y*v1.y + v1.z*v1.z + v1.w*v1.w;
  #pragma unroll
  for (int off = 1; off < 8; off <<= 1) {
    sum += __shfl_xor(sum, off);
    sq  += __shfl_xor(sq, off);
  }
  float mean = sum * (1.f / 64.f);
  float var  = sq * (1.f / 64.f) - mean * mean;
  float rstd = rsqrtf(var + LN_EPS);
  int n = n0 + node;
  if (n < N) {
    float4 ga0 = *(const float4*)&gam[fb], ga1 = *(const float4*)&gam[fb + 4];
    float4 be0 = *(const float4*)&bet[fb], be1 = *(const float4*)&bet[fb + 4];
    float4 o0, o1;
    o0.x = (v0.x - mean) * rstd * ga0.x + be0.x;
    o0.y = (v0.y - mean) * rstd * ga0.y + be0.y;
    o0.z = (v0.z - mean) * rstd * ga0.z + be0.z;
    o0.w = (v0.w - mean) * rstd * ga0.w + be0.w;
    o1.x = (v1.x - mean) * rstd * ga1.x + be1.x;
    o1.y = (v1.y - mean) * rstd * ga1.y + be1.y;
    o1.z = (v1.z - mean) * rstd * ga1.z + be1.z;
    o1.w = (v1.w - mean) * rstd * ga1.w + be1.w;
    float* op = &node_emb[(size_t)n * 64 + fb];
    *(float4*)(op + 0) = o0;
    *(float4*)(op + 4) = o1;
    int grp = batch[n];
    float* pp = &pooled[grp * 64 + fb];
    atomicAdd(pp + 0, o0.x); atomicAdd(pp + 1, o0.y);
    atomicAdd(pp + 2, o0.z); atomicAdd(pp + 3, o0.w);
    atomicAdd(pp + 4, o1.x); atomicAdd(pp + 5, o1.y);
    atomicAdd(pp + 6, o1.z); atomicAdd(pp + 7, o1.w);
    if (s == 0) atomicAdd(&counts[grp], 1.0f);
  }
}

__global__ __launch_bounds__(64) void graph_mean(
    const float* __restrict__ pooled, const float* __restrict__ counts,
    float* __restrict__ out) {
  int g = blockIdx.x, j = threadIdx.x;
  float inv = 1.f / fmaxf(counts[g], 1.f);
  out[g * 64 + j] = pooled[g * 64 + j] * inv;
}

extern "C" void kernel_launch(void* const* d_in, const int* in_sizes, int n_in,
                              void* d_out, int out_size, void* d_ws, size_t ws_size,
                              hipStream_t stream) {
  const float* x   = (const float*)d_in[0];
  const float* ef  = (const float*)d_in[1];
  const float* Ws0 = (const float*)d_in[2];
  const float* bs0 = (const float*)d_in[3];
  const float* Wm0 = (const float*)d_in[4];
  const float* bm0 = (const float*)d_in[5];
  const float* g0  = (const float*)d_in[6];
  const float* be0 = (const float*)d_in[7];
  const float* Ws1 = (const float*)d_in[8];
  const float* bs1 = (const float*)d_in[9];
  const float* Wm1 = (const float*)d_in[10];
  const float* bm1 = (const float*)d_in[11];
  const float* g1  = (const float*)d_in[12];
  const float* be1 = (const float*)d_in[13];
  const int* edge_index = (const int*)d_in[14];
  const int* batch = (const int*)d_in[15];

  const int N = in_sizes[0] / 128;
  const int E = in_sizes[14] / 2;
  const int G = 64;
  const int* src = edge_index;
  const int* tgt = edge_index + E;

  char* ws = (char*)d_ws;
  size_t off = 0;
  auto alloc = [&](size_t bytes) -> void* {
    void* p = ws + off;
    off = (off + bytes + 255) & ~(size_t)255;
    return p;
  };
  float* SX     = (float*)alloc((size_t)N * 128 * 4);  // reused as SH for layer 1
  float* SE     = (float*)alloc((size_t)N * 16 * 4);
  float* deg    = (float*)alloc((size_t)N * 4);
  float* h      = (float*)alloc((size_t)N * 128 * 4);
  int*   cnt    = (int*)alloc((size_t)N * 4);          // reused as cursor for fill
  int*   rowptr = (int*)alloc((size_t)(N + 1) * 4);
  int2*  csr    = (int2*)alloc((size_t)E * 8);
  float* pooled = (float*)alloc((size_t)G * 64 * 4);
  float* counts = (float*)alloc((size_t)G * 4);

  hipMemsetAsync(cnt, 0, (size_t)N * 4, stream);
  hipMemsetAsync(pooled, 0, (size_t)G * 64 * 4, stream);
  hipMemsetAsync(counts, 0, (size_t)G * 4, stream);

  hist_tgt<<<(E + 255) / 256, 256, 0, stream>>>(tgt, cnt, E);
  scan_rowptr<<<1, 1024, 0, stream>>>(cnt, rowptr, N);
  hipMemsetAsync(cnt, 0, (size_t)N * 4, stream);  // reuse as fill cursor
  fill_csr<<<(E + 255) / 256, 256, 0, stream>>>(src, tgt, rowptr, cnt, csr, E);

  agg0<<<(N + 1) / 2, 256, 0, stream>>>(x, ef, rowptr, csr, SX, SE, deg, N);

  layer0_gemm<<<(N + 31) / 32, 256, 0, stream>>>(
      x, SX, SE, deg, Ws0, Wm0, bs0, bm0, g0, be0, h, N);

  agg1<<<(N + 1) / 2, 256, 0, stream>>>(h, rowptr, csr, SX, N);

  layer1_gemm<<<(N + 31) / 32, 256, 0, stream>>>(
      h, SX, SE, deg, Ws1, Wm1, bs1, bm1, g1, be1, batch,
      (float*)d_out, pooled, counts, N);

  graph_mean<<<G, 64, 0, stream>>>(pooled, counts, (float*)d_out + (size_t)N * 64);
}

// Round 6
// 820.981 us; speedup vs baseline: 4.5689x; 1.7836x over previous
//
#include <hip/hip_runtime.h>

#define LN_EPS 1e-5f
#define KC 36
#define NCHUNK 8
#define UPAD 292   // u row stride (floats)

// ---- CSR build: histogram of tgt ----
__global__ __launch_bounds__(256) void hist_tgt(
    const int* __restrict__ tgt, int* __restrict__ cnt, int E) {
  int e = blockIdx.x * 256 + threadIdx.x;
  if (e < E) atomicAdd(&cnt[tgt[e]], 1);
}

// ---- CSR build: exclusive scan over cnt -> rowptr (single block) ----
__global__ __launch_bounds__(1024) void scan_rowptr(
    const int* __restrict__ cnt, int* __restrict__ rowptr, int N) {
  __shared__ int part[1024];
  int tid = threadIdx.x;
  int per = (N + 1023) / 1024;
  int start = tid * per;
  int end = min(start + per, N);
  int s = 0;
  for (int i = start; i < end; ++i) s += cnt[i];
  part[tid] = s;
  __syncthreads();
  for (int off = 1; off < 1024; off <<= 1) {
    int v = (tid >= off) ? part[tid - off] : 0;
    __syncthreads();
    part[tid] += v;
    __syncthreads();
  }
  int excl = (tid == 0) ? 0 : part[tid - 1];
  for (int i = start; i < end; ++i) {
    rowptr[i] = excl;
    excl += cnt[i];
  }
  if (tid == 1023) rowptr[N] = excl;
}

// ---- CSR build: fill (src, eid) pairs ----
__global__ __launch_bounds__(256) void fill_csr(
    const int* __restrict__ src, const int* __restrict__ tgt,
    const int* __restrict__ rowptr, int* __restrict__ cur,
    int2* __restrict__ csr, int E) {
  int e = blockIdx.x * 256 + threadIdx.x;
  if (e >= E) return;
  int t = tgt[e];
  int pos = atomicAdd(&cur[t], 1);
  csr[rowptr[t] + pos] = make_int2(src[e], e);
}

// ---- gather-aggregate layer 0: one wave per node, float2 per lane, 4-edge unroll ----
__global__ __launch_bounds__(256) void agg0(
    const float* __restrict__ x, const float* __restrict__ ef,
    const int* __restrict__ rowptr, const int2* __restrict__ csr,
    float* __restrict__ SX, float* __restrict__ SE,
    float* __restrict__ degF, int N) {
  int n = blockIdx.x * 4 + (threadIdx.x >> 6);
  if (n >= N) return;
  int lane = threadIdx.x & 63;
  int b = rowptr[n], e = rowptr[n + 1];
  float2 acc = make_float2(0.f, 0.f);
  float2 acce = make_float2(0.f, 0.f);
  int i = b;
  for (; i + 4 <= e; i += 4) {
    int2 p0 = csr[i], p1 = csr[i + 1], p2 = csr[i + 2], p3 = csr[i + 3];
    float2 v0 = *(const float2*)&x[(size_t)p0.x * 128 + lane * 2];
    float2 v1 = *(const float2*)&x[(size_t)p1.x * 128 + lane * 2];
    float2 v2 = *(const float2*)&x[(size_t)p2.x * 128 + lane * 2];
    float2 v3 = *(const float2*)&x[(size_t)p3.x * 128 + lane * 2];
    acc.x += (v0.x + v1.x) + (v2.x + v3.x);
    acc.y += (v0.y + v1.y) + (v2.y + v3.y);
    if (lane < 8) {
      float2 e0 = *(const float2*)&ef[(size_t)p0.y * 16 + lane * 2];
      float2 e1 = *(const float2*)&ef[(size_t)p1.y * 16 + lane * 2];
      float2 e2 = *(const float2*)&ef[(size_t)p2.y * 16 + lane * 2];
      float2 e3 = *(const float2*)&ef[(size_t)p3.y * 16 + lane * 2];
      acce.x += (e0.x + e1.x) + (e2.x + e3.x);
      acce.y += (e0.y + e1.y) + (e2.y + e3.y);
    }
  }
  for (; i < e; ++i) {
    int2 p = csr[i];
    float2 v = *(const float2*)&x[(size_t)p.x * 128 + lane * 2];
    acc.x += v.x; acc.y += v.y;
    if (lane < 8) {
      float2 ev = *(const float2*)&ef[(size_t)p.y * 16 + lane * 2];
      acce.x += ev.x; acce.y += ev.y;
    }
  }
  *(float2*)&SX[(size_t)n * 128 + lane * 2] = acc;
  if (lane < 8) *(float2*)&SE[(size_t)n * 16 + lane * 2] = acce;
  if (lane == 0) degF[n] = (float)(e - b);
}

// ---- gather-aggregate layer 1: SH[n] = sum h[src] ----
__global__ __launch_bounds__(256) void agg1(
    const float* __restrict__ h, const int* __restrict__ rowptr,
    const int2* __restrict__ csr, float* __restrict__ SH, int N) {
  int n = blockIdx.x * 4 + (threadIdx.x >> 6);
  if (n >= N) return;
  int lane = threadIdx.x & 63;
  int b = rowptr[n], e = rowptr[n + 1];
  float2 acc = make_float2(0.f, 0.f);
  int i = b;
  for (; i + 4 <= e; i += 4) {
    int2 p0 = csr[i], p1 = csr[i + 1], p2 = csr[i + 2], p3 = csr[i + 3];
    float2 v0 = *(const float2*)&h[(size_t)p0.x * 128 + lane * 2];
    float2 v1 = *(const float2*)&h[(size_t)p1.x * 128 + lane * 2];
    float2 v2 = *(const float2*)&h[(size_t)p2.x * 128 + lane * 2];
    float2 v3 = *(const float2*)&h[(size_t)p3.x * 128 + lane * 2];
    acc.x += (v0.x + v1.x) + (v2.x + v3.x);
    acc.y += (v0.y + v1.y) + (v2.y + v3.y);
  }
  for (; i < e; ++i) {
    int2 p = csr[i];
    float2 v = *(const float2*)&h[(size_t)p.x * 128 + lane * 2];
    acc.x += v.x; acc.y += v.y;
  }
  *(float2*)&SH[(size_t)n * 128 + lane * 2] = acc;
}

// ---- layer 0 GEMM: [32 nodes x 272] @ [272 x 128] + bias + LN + ReLU ----
__global__ __launch_bounds__(256) void layer0_gemm(
    const float* __restrict__ x, const float* __restrict__ SX,
    const float* __restrict__ SE, const float* __restrict__ deg,
    const float* __restrict__ Ws, const float* __restrict__ Wm,
    const float* __restrict__ bs, const float* __restrict__ bm,
    const float* __restrict__ gam, const float* __restrict__ bet,
    float* __restrict__ h, int N) {
  __shared__ float u[32][UPAD];
  __shared__ float wl[KC][128];
  __shared__ float dgs[32], dinv[32];
  int tid = threadIdx.x;
  int n0 = blockIdx.x * 32;
  if (tid < 32) {
    int n = n0 + tid;
    float dg = (n < N) ? deg[n] : 0.f;
    dgs[tid] = dg;
    dinv[tid] = dg > 0.f ? 1.f / dg : 0.f;
  }
  __syncthreads();
  for (int idx = tid; idx < 32 * 128; idx += 256) {
    int m = idx >> 7, f = idx & 127;
    int n = n0 + m;
    if (n < N) {
      u[m][f]       = x[(size_t)n * 128 + f];
      u[m][128 + f] = SX[(size_t)n * 128 + f] * dinv[m];
    } else { u[m][f] = 0.f; u[m][128 + f] = 0.f; }
  }
  for (int idx = tid; idx < 32 * 32; idx += 256) {
    int m = idx >> 5, f = idx & 31;
    int n = n0 + m;
    u[m][256 + f] = (f < 16 && n < N) ? SE[(size_t)n * 16 + f] * dinv[m] : 0.f;
  }

  int tn = tid >> 5, tj = tid & 31;
  int jb = tj * 4;
  float acc[4][4];
  #pragma unroll
  for (int m = 0; m < 4; ++m) {
    bool has = dgs[tn * 4 + m] > 0.f;
    #pragma unroll
    for (int q = 0; q < 4; ++q)
      acc[m][q] = bs[jb + q] + (has ? bm[jb + q] : 0.f);
  }

  for (int c = 0; c < NCHUNK; ++c) {
    if (c) __syncthreads();
    for (int idx = tid; idx < KC * 128; idx += 256) {
      int kk = idx >> 7, j = idx & 127;
      int k = c * KC + kk;
      float v = 0.f;
      if (k < 128) v = Ws[k * 128 + j];
      else if (k < 272) v = Wm[(k - 128) * 128 + j];
      wl[kk][j] = v;
    }
    __syncthreads();
    #pragma unroll 3
    for (int kk = 0; kk < KC; kk += 4) {
      float4 uv[4], wv[4];
      #pragma unroll
      for (int m = 0; m < 4; ++m) uv[m] = *(const float4*)&u[tn * 4 + m][c * KC + kk];
      #pragma unroll
      for (int t = 0; t < 4; ++t) wv[t] = *(const float4*)&wl[kk + t][jb];
      #pragma unroll
      for (int m = 0; m < 4; ++m) {
        float us[4] = {uv[m].x, uv[m].y, uv[m].z, uv[m].w};
        #pragma unroll
        for (int t = 0; t < 4; ++t) {
          acc[m][0] = fmaf(us[t], wv[t].x, acc[m][0]);
          acc[m][1] = fmaf(us[t], wv[t].y, acc[m][1]);
          acc[m][2] = fmaf(us[t], wv[t].z, acc[m][2]);
          acc[m][3] = fmaf(us[t], wv[t].w, acc[m][3]);
        }
      }
    }
  }

  __syncthreads();
  #pragma unroll
  for (int m = 0; m < 4; ++m)
    *(float4*)&u[tn * 4 + m][jb] = make_float4(acc[m][0], acc[m][1], acc[m][2], acc[m][3]);
  __syncthreads();

  int node = tid >> 3, s = tid & 7;
  int fb = s * 16;
  float4 v0 = *(const float4*)&u[node][fb];
  float4 v1 = *(const float4*)&u[node][fb + 4];
  float4 v2 = *(const float4*)&u[node][fb + 8];
  float4 v3 = *(const float4*)&u[node][fb + 12];
  float sum = v0.x + v0.y + v0.z + v0.w + v1.x + v1.y + v1.z + v1.w
            + v2.x + v2.y + v2.z + v2.w + v3.x + v3.y + v3.z + v3.w;
  float sq  = v0.x*v0.x + v0.y*v0.y + v0.z*v0.z + v0.w*v0.w
            + v1.x*v1.x + v1.y*v1.y + v1.z*v1.z + v1.w*v1.w
            + v2.x*v2.x + v2.y*v2.y + v2.z*v2.z + v2.w*v2.w
            + v3.x*v3.x + v3.y*v3.y + v3.z*v3.z + v3.w*v3.w;
  #pragma unroll
  for (int off = 1; off < 8; off <<= 1) {
    sum += __shfl_xor(sum, off);
    sq  += __shfl_xor(sq, off);
  }
  float mean = sum * (1.f / 128.f);
  float var  = sq * (1.f / 128.f) - mean * mean;
  float rstd = rsqrtf(var + LN_EPS);
  int n = n0 + node;
  if (n < N) {
    float4 ga0 = *(const float4*)&gam[fb],     ga1 = *(const float4*)&gam[fb + 4];
    float4 ga2 = *(const float4*)&gam[fb + 8], ga3 = *(const float4*)&gam[fb + 12];
    float4 be0 = *(const float4*)&bet[fb],     be1 = *(const float4*)&bet[fb + 4];
    float4 be2 = *(const float4*)&bet[fb + 8], be3 = *(const float4*)&bet[fb + 12];
    float* hp = &h[(size_t)n * 128 + fb];
    float4 o;
    o.x = fmaxf((v0.x - mean) * rstd * ga0.x + be0.x, 0.f);
    o.y = fmaxf((v0.y - mean) * rstd * ga0.y + be0.y, 0.f);
    o.z = fmaxf((v0.z - mean) * rstd * ga0.z + be0.z, 0.f);
    o.w = fmaxf((v0.w - mean) * rstd * ga0.w + be0.w, 0.f);
    *(float4*)(hp + 0) = o;
    o.x = fmaxf((v1.x - mean) * rstd * ga1.x + be1.x, 0.f);
    o.y = fmaxf((v1.y - mean) * rstd * ga1.y + be1.y, 0.f);
    o.z = fmaxf((v1.z - mean) * rstd * ga1.z + be1.z, 0.f);
    o.w = fmaxf((v1.w - mean) * rstd * ga1.w + be1.w, 0.f);
    *(float4*)(hp + 4) = o;
    o.x = fmaxf((v2.x - mean) * rstd * ga2.x + be2.x, 0.f);
    o.y = fmaxf((v2.y - mean) * rstd * ga2.y + be2.y, 0.f);
    o.z = fmaxf((v2.z - mean) * rstd * ga2.z + be2.z, 0.f);
    o.w = fmaxf((v2.w - mean) * rstd * ga2.w + be2.w, 0.f);
    *(float4*)(hp + 8) = o;
    o.x = fmaxf((v3.x - mean) * rstd * ga3.x + be3.x, 0.f);
    o.y = fmaxf((v3.y - mean) * rstd * ga3.y + be3.y, 0.f);
    o.z = fmaxf((v3.z - mean) * rstd * ga3.z + be3.z, 0.f);
    o.w = fmaxf((v3.w - mean) * rstd * ga3.w + be3.w, 0.f);
    *(float4*)(hp + 12) = o;
  }
}

// ---- layer 1 GEMM: [32 nodes x 272] @ [272 x 64] + bias + LN (no atomics) ----
__global__ __launch_bounds__(256) void layer1_gemm(
    const float* __restrict__ hin, const float* __restrict__ SH,
    const float* __restrict__ SE, const float* __restrict__ deg,
    const float* __restrict__ Ws, const float* __restrict__ Wm,
    const float* __restrict__ bs, const float* __restrict__ bm,
    const float* __restrict__ gam, const float* __restrict__ bet,
    float* __restrict__ node_emb, int N) {
  __shared__ float u[32][UPAD];
  __shared__ float wl[KC][64];
  __shared__ float dgs[32], dinv[32];
  int tid = threadIdx.x;
  int n0 = blockIdx.x * 32;
  if (tid < 32) {
    int n = n0 + tid;
    float dg = (n < N) ? deg[n] : 0.f;
    dgs[tid] = dg;
    dinv[tid] = dg > 0.f ? 1.f / dg : 0.f;
  }
  __syncthreads();
  for (int idx = tid; idx < 32 * 128; idx += 256) {
    int m = idx >> 7, f = idx & 127;
    int n = n0 + m;
    if (n < N) {
      u[m][f]       = hin[(size_t)n * 128 + f];
      u[m][128 + f] = SH[(size_t)n * 128 + f] * dinv[m];
    } else { u[m][f] = 0.f; u[m][128 + f] = 0.f; }
  }
  for (int idx = tid; idx < 32 * 32; idx += 256) {
    int m = idx >> 5, f = idx & 31;
    int n = n0 + m;
    u[m][256 + f] = (f < 16 && n < N) ? SE[(size_t)n * 16 + f] * dinv[m] : 0.f;
  }

  int tn = tid >> 5, tj = tid & 31;
  int jb = tj * 2;
  float acc[4][2];
  #pragma unroll
  for (int m = 0; m < 4; ++m) {
    bool has = dgs[tn * 4 + m] > 0.f;
    #pragma unroll
    for (int q = 0; q < 2; ++q)
      acc[m][q] = bs[jb + q] + (has ? bm[jb + q] : 0.f);
  }

  for (int c = 0; c < NCHUNK; ++c) {
    if (c) __syncthreads();
    for (int idx = tid; idx < KC * 64; idx += 256) {
      int kk = idx >> 6, j = idx & 63;
      int k = c * KC + kk;
      float v = 0.f;
      if (k < 128) v = Ws[k * 64 + j];
      else if (k < 272) v = Wm[(k - 128) * 64 + j];
      wl[kk][j] = v;
    }
    __syncthreads();
    #pragma unroll 3
    for (int kk = 0; kk < KC; kk += 4) {
      float4 uv[4];
      float2 wv[4];
      #pragma unroll
      for (int m = 0; m < 4; ++m) uv[m] = *(const float4*)&u[tn * 4 + m][c * KC + kk];
      #pragma unroll
      for (int t = 0; t < 4; ++t) wv[t] = *(const float2*)&wl[kk + t][jb];
      #pragma unroll
      for (int m = 0; m < 4; ++m) {
        float us[4] = {uv[m].x, uv[m].y, uv[m].z, uv[m].w};
        #pragma unroll
        for (int t = 0; t < 4; ++t) {
          acc[m][0] = fmaf(us[t], wv[t].x, acc[m][0]);
          acc[m][1] = fmaf(us[t], wv[t].y, acc[m][1]);
        }
      }
    }
  }

  __syncthreads();
  #pragma unroll
  for (int m = 0; m < 4; ++m)
    *(float2*)&u[tn * 4 + m][jb] = make_float2(acc[m][0], acc[m][1]);
  __syncthreads();

  int node = tid >> 3, s = tid & 7;
  int fb = s * 8;
  float4 v0 = *(const float4*)&u[node][fb];
  float4 v1 = *(const float4*)&u[node][fb + 4];
  float sum = v0.x + v0.y + v0.z + v0.w + v1.x + v1.y + v1.z + v1.w;
  float sq  = v0.x*v0.x + v0.y*v0.y + v0.z*v0.z + v0.w*v0.w
            + v1.x*v1.x + v1.y*v1.y + v1.z*v1.z + v1.w*v1.w;
  #pragma unroll
  for (int off = 1; off < 8; off <<= 1) {
    sum += __shfl_xor(sum, off);
    sq  += __shfl_xor(sq, off);
  }
  float mean = sum * (1.f / 64.f);
  float var  = sq * (1.f / 64.f) - mean * mean;
  float rstd = rsqrtf(var + LN_EPS);
  int n = n0 + node;
  if (n < N) {
    float4 ga0 = *(const float4*)&gam[fb], ga1 = *(const float4*)&gam[fb + 4];
    float4 be0 = *(const float4*)&bet[fb], be1 = *(const float4*)&bet[fb + 4];
    float4 o0, o1;
    o0.x = (v0.x - mean) * rstd * ga0.x + be0.x;
    o0.y = (v0.y - mean) * rstd * ga0.y + be0.y;
    o0.z = (v0.z - mean) * rstd * ga0.z + be0.z;
    o0.w = (v0.w - mean) * rstd * ga0.w + be0.w;
    o1.x = (v1.x - mean) * rstd * ga1.x + be1.x;
    o1.y = (v1.y - mean) * rstd * ga1.y + be1.y;
    o1.z = (v1.z - mean) * rstd * ga1.z + be1.z;
    o1.w = (v1.w - mean) * rstd * ga1.w + be1.w;
    float* op = &node_emb[(size_t)n * 64 + fb];
    *(float4*)(op + 0) = o0;
    *(float4*)(op + 4) = o1;
  }
}

// ---- graph pooling: batch is sorted; block g segment-sums node_emb[lo:hi) ----
__global__ __launch_bounds__(256) void graph_pool(
    const float* __restrict__ node_emb, const int* __restrict__ batch,
    float* __restrict__ out, int N) {
  __shared__ float red[4][64];
  int g = blockIdx.x;
  int tid = threadIdx.x;
  int j = tid & 63, c = tid >> 6;
  int lo = 0, hi = N;
  while (lo < hi) { int mid = (lo + hi) >> 1; if (batch[mid] < g) lo = mid + 1; else hi = mid; }
  int start = lo;
  lo = 0; hi = N;
  while (lo < hi) { int mid = (lo + hi) >> 1; if (batch[mid] < g + 1) lo = mid + 1; else hi = mid; }
  int end = lo;
  float s = 0.f;
  for (int n = start + c; n < end; n += 4)
    s += node_emb[(size_t)n * 64 + j];
  red[c][j] = s;
  __syncthreads();
  if (c == 0) {
    float tot = red[0][j] + red[1][j] + red[2][j] + red[3][j];
    float inv = 1.f / fmaxf((float)(end - start), 1.f);
    out[g * 64 + j] = tot * inv;
  }
}

extern "C" void kernel_launch(void* const* d_in, const int* in_sizes, int n_in,
                              void* d_out, int out_size, void* d_ws, size_t ws_size,
                              hipStream_t stream) {
  const float* x   = (const float*)d_in[0];
  const float* ef  = (const float*)d_in[1];
  const float* Ws0 = (const float*)d_in[2];
  const float* bs0 = (const float*)d_in[3];
  const float* Wm0 = (const float*)d_in[4];
  const float* bm0 = (const float*)d_in[5];
  const float* g0  = (const float*)d_in[6];
  const float* be0 = (const float*)d_in[7];
  const float* Ws1 = (const float*)d_in[8];
  const float* bs1 = (const float*)d_in[9];
  const float* Wm1 = (const float*)d_in[10];
  const float* bm1 = (const float*)d_in[11];
  const float* g1  = (const float*)d_in[12];
  const float* be1 = (const float*)d_in[13];
  const int* edge_index = (const int*)d_in[14];
  const int* batch = (const int*)d_in[15];

  const int N = in_sizes[0] / 128;
  const int E = in_sizes[14] / 2;
  const int G = 64;
  const int* src = edge_index;
  const int* tgt = edge_index + E;

  char* ws = (char*)d_ws;
  size_t off = 0;
  auto alloc = [&](size_t bytes) -> void* {
    void* p = ws + off;
    off = (off + bytes + 255) & ~(size_t)255;
    return p;
  };
  float* SX     = (float*)alloc((size_t)N * 128 * 4);  // reused as SH for layer 1
  float* SE     = (float*)alloc((size_t)N * 16 * 4);
  float* deg    = (float*)alloc((size_t)N * 4);
  float* h      = (float*)alloc((size_t)N * 128 * 4);
  int*   cnt    = (int*)alloc((size_t)N * 4);          // reused as cursor for fill
  int*   rowptr = (int*)alloc((size_t)(N + 1) * 4);
  int2*  csr    = (int2*)alloc((size_t)E * 8);

  hipMemsetAsync(cnt, 0, (size_t)N * 4, stream);

  hist_tgt<<<(E + 255) / 256, 256, 0, stream>>>(tgt, cnt, E);
  scan_rowptr<<<1, 1024, 0, stream>>>(cnt, rowptr, N);
  hipMemsetAsync(cnt, 0, (size_t)N * 4, stream);  // reuse as fill cursor
  fill_csr<<<(E + 255) / 256, 256, 0, stream>>>(src, tgt, rowptr, cnt, csr, E);

  agg0<<<(N + 3) / 4, 256, 0, stream>>>(x, ef, rowptr, csr, SX, SE, deg, N);

  layer0_gemm<<<(N + 31) / 32, 256, 0, stream>>>(
      x, SX, SE, deg, Ws0, Wm0, bs0, bm0, g0, be0, h, N);

  agg1<<<(N + 3) / 4, 256, 0, stream>>>(h, rowptr, csr, SX, N);

  layer1_gemm<<<(N + 31) / 32, 256, 0, stream>>>(
      h, SX, SE, deg, Ws1, Wm1, bs1, bm1, g1, be1, (float*)d_out, N);

  graph_pool<<<G, 256, 0, stream>>>((const float*)d_out, batch,
                                    (float*)d_out + (size_t)N * 64, N);
}

// Round 8
// 621.131 us; speedup vs baseline: 6.0390x; 1.3218x over previous
//
#include <hip/hip_runtime.h>

#define LN_EPS 1e-5f
#define UPAD 292   // u row stride (floats)

// ---- CSR build: histogram of tgt ----
__global__ __launch_bounds__(256) void hist_tgt(
    const int* __restrict__ tgt, int* __restrict__ cnt, int E) {
  int e = blockIdx.x * 256 + threadIdx.x;
  if (e < E) atomicAdd(&cnt[tgt[e]], 1);
}

// ---- CSR build: exclusive scan over cnt -> rowptr (single block) ----
__global__ __launch_bounds__(1024) void scan_rowptr(
    const int* __restrict__ cnt, int* __restrict__ rowptr, int N) {
  __shared__ int part[1024];
  int tid = threadIdx.x;
  int per = (N + 1023) / 1024;
  int start = tid * per;
  int end = min(start + per, N);
  int s = 0;
  for (int i = start; i < end; ++i) s += cnt[i];
  part[tid] = s;
  __syncthreads();
  for (int off = 1; off < 1024; off <<= 1) {
    int v = (tid >= off) ? part[tid - off] : 0;
    __syncthreads();
    part[tid] += v;
    __syncthreads();
  }
  int excl = (tid == 0) ? 0 : part[tid - 1];
  for (int i = start; i < end; ++i) {
    rowptr[i] = excl;
    excl += cnt[i];
  }
  if (tid == 1023) rowptr[N] = excl;
}

// ---- CSR build: fill (src, eid) pairs ----
__global__ __launch_bounds__(256) void fill_csr(
    const int* __restrict__ src, const int* __restrict__ tgt,
    const int* __restrict__ rowptr, int* __restrict__ cur,
    int2* __restrict__ csr, int E) {
  int e = blockIdx.x * 256 + threadIdx.x;
  if (e >= E) return;
  int t = tgt[e];
  int pos = atomicAdd(&cur[t], 1);
  csr[rowptr[t] + pos] = make_int2(src[e], e);
}

// ---- gather-aggregate layer 0: one wave per node, float2 per lane, 4-edge unroll ----
__global__ __launch_bounds__(256) void agg0(
    const float* __restrict__ x, const float* __restrict__ ef,
    const int* __restrict__ rowptr, const int2* __restrict__ csr,
    float* __restrict__ SX, float* __restrict__ SE,
    float* __restrict__ degF, int N) {
  int n = blockIdx.x * 4 + (threadIdx.x >> 6);
  if (n >= N) return;
  int lane = threadIdx.x & 63;
  int b = rowptr[n], e = rowptr[n + 1];
  float2 acc = make_float2(0.f, 0.f);
  float2 acce = make_float2(0.f, 0.f);
  int i = b;
  for (; i + 4 <= e; i += 4) {
    int2 p0 = csr[i], p1 = csr[i + 1], p2 = csr[i + 2], p3 = csr[i + 3];
    float2 v0 = *(const float2*)&x[(size_t)p0.x * 128 + lane * 2];
    float2 v1 = *(const float2*)&x[(size_t)p1.x * 128 + lane * 2];
    float2 v2 = *(const float2*)&x[(size_t)p2.x * 128 + lane * 2];
    float2 v3 = *(const float2*)&x[(size_t)p3.x * 128 + lane * 2];
    acc.x += (v0.x + v1.x) + (v2.x + v3.x);
    acc.y += (v0.y + v1.y) + (v2.y + v3.y);
    if (lane < 8) {
      float2 e0 = *(const float2*)&ef[(size_t)p0.y * 16 + lane * 2];
      float2 e1 = *(const float2*)&ef[(size_t)p1.y * 16 + lane * 2];
      float2 e2 = *(const float2*)&ef[(size_t)p2.y * 16 + lane * 2];
      float2 e3 = *(const float2*)&ef[(size_t)p3.y * 16 + lane * 2];
      acce.x += (e0.x + e1.x) + (e2.x + e3.x);
      acce.y += (e0.y + e1.y) + (e2.y + e3.y);
    }
  }
  for (; i < e; ++i) {
    int2 p = csr[i];
    float2 v = *(const float2*)&x[(size_t)p.x * 128 + lane * 2];
    acc.x += v.x; acc.y += v.y;
    if (lane < 8) {
      float2 ev = *(const float2*)&ef[(size_t)p.y * 16 + lane * 2];
      acce.x += ev.x; acce.y += ev.y;
    }
  }
  *(float2*)&SX[(size_t)n * 128 + lane * 2] = acc;
  if (lane < 8) *(float2*)&SE[(size_t)n * 16 + lane * 2] = acce;
  if (lane == 0) degF[n] = (float)(e - b);
}

// ---- gather-aggregate layer 1: SH[n] = sum h[src] ----
__global__ __launch_bounds__(256) void agg1(
    const float* __restrict__ h, const int* __restrict__ rowptr,
    const int2* __restrict__ csr, float* __restrict__ SH, int N) {
  int n = blockIdx.x * 4 + (threadIdx.x >> 6);
  if (n >= N) return;
  int lane = threadIdx.x & 63;
  int b = rowptr[n], e = rowptr[n + 1];
  float2 acc = make_float2(0.f, 0.f);
  int i = b;
  for (; i + 4 <= e; i += 4) {
    int2 p0 = csr[i], p1 = csr[i + 1], p2 = csr[i + 2], p3 = csr[i + 3];
    float2 v0 = *(const float2*)&h[(size_t)p0.x * 128 + lane * 2];
    float2 v1 = *(const float2*)&h[(size_t)p1.x * 128 + lane * 2];
    float2 v2 = *(const float2*)&h[(size_t)p2.x * 128 + lane * 2];
    float2 v3 = *(const float2*)&h[(size_t)p3.x * 128 + lane * 2];
    acc.x += (v0.x + v1.x) + (v2.x + v3.x);
    acc.y += (v0.y + v1.y) + (v2.y + v3.y);
  }
  for (; i < e; ++i) {
    int2 p = csr[i];
    float2 v = *(const float2*)&h[(size_t)p.x * 128 + lane * 2];
    acc.x += v.x; acc.y += v.y;
  }
  *(float2*)&SH[(size_t)n * 128 + lane * 2] = acc;
}

// ---- layer 0 GEMM: [32 nodes x 272] @ [272 x 128] + bias + LN + ReLU ----
// No weight LDS staging: weights read direct from global (L1/L2-resident),
// barrier-free K-loop, 4 blocks/CU.
__global__ __launch_bounds__(256, 4) void layer0_gemm(
    const float* __restrict__ x, const float* __restrict__ SX,
    const float* __restrict__ SE, const float* __restrict__ deg,
    const float* __restrict__ Ws, const float* __restrict__ Wm,
    const float* __restrict__ bs, const float* __restrict__ bm,
    const float* __restrict__ gam, const float* __restrict__ bet,
    float* __restrict__ h, int N) {
  __shared__ float u[32][UPAD];
  __shared__ float dgs[32], dinv[32];
  int tid = threadIdx.x;
  int n0 = blockIdx.x * 32;
  if (tid < 32) {
    int n = n0 + tid;
    float dg = (n < N) ? deg[n] : 0.f;
    dgs[tid] = dg;
    dinv[tid] = dg > 0.f ? 1.f / dg : 0.f;
  }
  __syncthreads();
  // stage u: x | SX/deg | SE/deg (float4 vectorized)
  for (int idx = tid; idx < 1024; idx += 256) {
    int m = idx >> 5, f = (idx & 31) * 4;
    int n = n0 + m;
    float4 xv = make_float4(0.f, 0.f, 0.f, 0.f), sv = xv;
    if (n < N) {
      xv = *(const float4*)&x[(size_t)n * 128 + f];
      sv = *(const float4*)&SX[(size_t)n * 128 + f];
      float di = dinv[m];
      sv.x *= di; sv.y *= di; sv.z *= di; sv.w *= di;
    }
    *(float4*)&u[m][f] = xv;
    *(float4*)&u[m][128 + f] = sv;
  }
  if (tid < 128) {
    int m = tid >> 2, f = (tid & 3) * 4;
    int n = n0 + m;
    float4 ev = make_float4(0.f, 0.f, 0.f, 0.f);
    if (n < N) {
      ev = *(const float4*)&SE[(size_t)n * 16 + f];
      float di = dinv[m];
      ev.x *= di; ev.y *= di; ev.z *= di; ev.w *= di;
    }
    *(float4*)&u[m][256 + f] = ev;
  }
  __syncthreads();

  int tn = tid >> 5, tj = tid & 31;
  int jb = tj * 4;
  float4 bsv = *(const float4*)&bs[jb];
  float4 bmv = *(const float4*)&bm[jb];
  float acc[4][4];
  #pragma unroll
  for (int m = 0; m < 4; ++m) {
    bool has = dgs[tn * 4 + m] > 0.f;
    acc[m][0] = bsv.x + (has ? bmv.x : 0.f);
    acc[m][1] = bsv.y + (has ? bmv.y : 0.f);
    acc[m][2] = bsv.z + (has ? bmv.z : 0.f);
    acc[m][3] = bsv.w + (has ? bmv.w : 0.f);
  }

  // k-loop part 1: Ws over u[:,0:128]
  #pragma unroll 2
  for (int k = 0; k < 128; k += 4) {
    float4 wv[4], uv[4];
    #pragma unroll
    for (int t = 0; t < 4; ++t) wv[t] = *(const float4*)&Ws[(size_t)(k + t) * 128 + jb];
    #pragma unroll
    for (int m = 0; m < 4; ++m) uv[m] = *(const float4*)&u[tn * 4 + m][k];
    #pragma unroll
    for (int m = 0; m < 4; ++m) {
      float us[4] = {uv[m].x, uv[m].y, uv[m].z, uv[m].w};
      #pragma unroll
      for (int t = 0; t < 4; ++t) {
        acc[m][0] = fmaf(us[t], wv[t].x, acc[m][0]);
        acc[m][1] = fmaf(us[t], wv[t].y, acc[m][1]);
        acc[m][2] = fmaf(us[t], wv[t].z, acc[m][2]);
        acc[m][3] = fmaf(us[t], wv[t].w, acc[m][3]);
      }
    }
  }
  // k-loop part 2: Wm over u[:,128:272]
  #pragma unroll 2
  for (int k = 0; k < 144; k += 4) {
    float4 wv[4], uv[4];
    #pragma unroll
    for (int t = 0; t < 4; ++t) wv[t] = *(const float4*)&Wm[(size_t)(k + t) * 128 + jb];
    #pragma unroll
    for (int m = 0; m < 4; ++m) uv[m] = *(const float4*)&u[tn * 4 + m][128 + k];
    #pragma unroll
    for (int m = 0; m < 4; ++m) {
      float us[4] = {uv[m].x, uv[m].y, uv[m].z, uv[m].w};
      #pragma unroll
      for (int t = 0; t < 4; ++t) {
        acc[m][0] = fmaf(us[t], wv[t].x, acc[m][0]);
        acc[m][1] = fmaf(us[t], wv[t].y, acc[m][1]);
        acc[m][2] = fmaf(us[t], wv[t].z, acc[m][2]);
        acc[m][3] = fmaf(us[t], wv[t].w, acc[m][3]);
      }
    }
  }

  __syncthreads();
  #pragma unroll
  for (int m = 0; m < 4; ++m)
    *(float4*)&u[tn * 4 + m][jb] = make_float4(acc[m][0], acc[m][1], acc[m][2], acc[m][3]);
  __syncthreads();

  int node = tid >> 3, s = tid & 7;
  int fb = s * 16;
  float4 v0 = *(const float4*)&u[node][fb];
  float4 v1 = *(const float4*)&u[node][fb + 4];
  float4 v2 = *(const float4*)&u[node][fb + 8];
  float4 v3 = *(const float4*)&u[node][fb + 12];
  float sum = v0.x + v0.y + v0.z + v0.w + v1.x + v1.y + v1.z + v1.w
            + v2.x + v2.y + v2.z + v2.w + v3.x + v3.y + v3.z + v3.w;
  float sq  = v0.x*v0.x + v0.y*v0.y + v0.z*v0.z + v0.w*v0.w
            + v1.x*v1.x + v1.y*v1.y + v1.z*v1.z + v1.w*v1.w
            + v2.x*v2.x + v2.y*v2.y + v2.z*v2.z + v2.w*v2.w
            + v3.x*v3.x + v3.y*v3.y + v3.z*v3.z + v3.w*v3.w;
  #pragma unroll
  for (int off = 1; off < 8; off <<= 1) {
    sum += __shfl_xor(sum, off);
    sq  += __shfl_xor(sq, off);
  }
  float mean = sum * (1.f / 128.f);
  float var  = sq * (1.f / 128.f) - mean * mean;
  float rstd = rsqrtf(var + LN_EPS);
  int n = n0 + node;
  if (n < N) {
    float4 ga0 = *(const float4*)&gam[fb],     ga1 = *(const float4*)&gam[fb + 4];
    float4 ga2 = *(const float4*)&gam[fb + 8], ga3 = *(const float4*)&gam[fb + 12];
    float4 be0 = *(const float4*)&bet[fb],     be1 = *(const float4*)&bet[fb + 4];
    float4 be2 = *(const float4*)&bet[fb + 8], be3 = *(const float4*)&bet[fb + 12];
    float* hp = &h[(size_t)n * 128 + fb];
    float4 o;
    o.x = fmaxf((v0.x - mean) * rstd * ga0.x + be0.x, 0.f);
    o.y = fmaxf((v0.y - mean) * rstd * ga0.y + be0.y, 0.f);
    o.z = fmaxf((v0.z - mean) * rstd * ga0.z + be0.z, 0.f);
    o.w = fmaxf((v0.w - mean) * rstd * ga0.w + be0.w, 0.f);
    *(float4*)(hp + 0) = o;
    o.x = fmaxf((v1.x - mean) * rstd * ga1.x + be1.x, 0.f);
    o.y = fmaxf((v1.y - mean) * rstd * ga1.y + be1.y, 0.f);
    o.z = fmaxf((v1.z - mean) * rstd * ga1.z + be1.z, 0.f);
    o.w = fmaxf((v1.w - mean) * rstd * ga1.w + be1.w, 0.f);
    *(float4*)(hp + 4) = o;
    o.x = fmaxf((v2.x - mean) * rstd * ga2.x + be2.x, 0.f);
    o.y = fmaxf((v2.y - mean) * rstd * ga2.y + be2.y, 0.f);
    o.z = fmaxf((v2.z - mean) * rstd * ga2.z + be2.z, 0.f);
    o.w = fmaxf((v2.w - mean) * rstd * ga2.w + be2.w, 0.f);
    *(float4*)(hp + 8) = o;
    o.x = fmaxf((v3.x - mean) * rstd * ga3.x + be3.x, 0.f);
    o.y = fmaxf((v3.y - mean) * rstd * ga3.y + be3.y, 0.f);
    o.z = fmaxf((v3.z - mean) * rstd * ga3.z + be3.z, 0.f);
    o.w = fmaxf((v3.w - mean) * rstd * ga3.w + be3.w, 0.f);
    *(float4*)(hp + 12) = o;
  }
}

// ---- layer 1 GEMM: [32 nodes x 272] @ [272 x 64] + bias + LN (no atomics) ----
__global__ __launch_bounds__(256, 4) void layer1_gemm(
    const float* __restrict__ hin, const float* __restrict__ SH,
    const float* __restrict__ SE, const float* __restrict__ deg,
    const float* __restrict__ Ws, const float* __restrict__ Wm,
    const float* __restrict__ bs, const float* __restrict__ bm,
    const float* __restrict__ gam, const float* __restrict__ bet,
    float* __restrict__ node_emb, int N) {
  __shared__ float u[32][UPAD];
  __shared__ float dgs[32], dinv[32];
  int tid = threadIdx.x;
  int n0 = blockIdx.x * 32;
  if (tid < 32) {
    int n = n0 + tid;
    float dg = (n < N) ? deg[n] : 0.f;
    dgs[tid] = dg;
    dinv[tid] = dg > 0.f ? 1.f / dg : 0.f;
  }
  __syncthreads();
  for (int idx = tid; idx < 1024; idx += 256) {
    int m = idx >> 5, f = (idx & 31) * 4;
    int n = n0 + m;
    float4 xv = make_float4(0.f, 0.f, 0.f, 0.f), sv = xv;
    if (n < N) {
      xv = *(const float4*)&hin[(size_t)n * 128 + f];
      sv = *(const float4*)&SH[(size_t)n * 128 + f];
      float di = dinv[m];
      sv.x *= di; sv.y *= di; sv.z *= di; sv.w *= di;
    }
    *(float4*)&u[m][f] = xv;
    *(float4*)&u[m][128 + f] = sv;
  }
  if (tid < 128) {
    int m = tid >> 2, f = (tid & 3) * 4;
    int n = n0 + m;
    float4 ev = make_float4(0.f, 0.f, 0.f, 0.f);
    if (n < N) {
      ev = *(const float4*)&SE[(size_t)n * 16 + f];
      float di = dinv[m];
      ev.x *= di; ev.y *= di; ev.z *= di; ev.w *= di;
    }
    *(float4*)&u[m][256 + f] = ev;
  }
  __syncthreads();

  int tn = tid >> 5, tj = tid & 31;
  int jb = tj * 2;
  float2 bsv = *(const float2*)&bs[jb];
  float2 bmv = *(const float2*)&bm[jb];
  float acc[4][2];
  #pragma unroll
  for (int m = 0; m < 4; ++m) {
    bool has = dgs[tn * 4 + m] > 0.f;
    acc[m][0] = bsv.x + (has ? bmv.x : 0.f);
    acc[m][1] = bsv.y + (has ? bmv.y : 0.f);
  }

  #pragma unroll 2
  for (int k = 0; k < 128; k += 4) {
    float2 wv[4];
    float4 uv[4];
    #pragma unroll
    for (int t = 0; t < 4; ++t) wv[t] = *(const float2*)&Ws[(size_t)(k + t) * 64 + jb];
    #pragma unroll
    for (int m = 0; m < 4; ++m) uv[m] = *(const float4*)&u[tn * 4 + m][k];
    #pragma unroll
    for (int m = 0; m < 4; ++m) {
      float us[4] = {uv[m].x, uv[m].y, uv[m].z, uv[m].w};
      #pragma unroll
      for (int t = 0; t < 4; ++t) {
        acc[m][0] = fmaf(us[t], wv[t].x, acc[m][0]);
        acc[m][1] = fmaf(us[t], wv[t].y, acc[m][1]);
      }
    }
  }
  #pragma unroll 2
  for (int k = 0; k < 144; k += 4) {
    float2 wv[4];
    float4 uv[4];
    #pragma unroll
    for (int t = 0; t < 4; ++t) wv[t] = *(const float2*)&Wm[(size_t)(k + t) * 64 + jb];
    #pragma unroll
    for (int m = 0; m < 4; ++m) uv[m] = *(const float4*)&u[tn * 4 + m][128 + k];
    #pragma unroll
    for (int m = 0; m < 4; ++m) {
      float us[4] = {uv[m].x, uv[m].y, uv[m].z, uv[m].w};
      #pragma unroll
      for (int t = 0; t < 4; ++t) {
        acc[m][0] = fmaf(us[t], wv[t].x, acc[m][0]);
        acc[m][1] = fmaf(us[t], wv[t].y, acc[m][1]);
      }
    }
  }

  __syncthreads();
  #pragma unroll
  for (int m = 0; m < 4; ++m)
    *(float2*)&u[tn * 4 + m][jb] = make_float2(acc[m][0], acc[m][1]);
  __syncthreads();

  int node = tid >> 3, s = tid & 7;
  int fb = s * 8;
  float4 v0 = *(const float4*)&u[node][fb];
  float4 v1 = *(const float4*)&u[node][fb + 4];
  float sum = v0.x + v0.y + v0.z + v0.w + v1.x + v1.y + v1.z + v1.w;
  float sq  = v0.x*v0.x + v0.y*v0.y + v0.z*v0.z + v0.w*v0.w
            + v1.x*v1.x + v1.y*v1.y + v1.z*v1.z + v1.w*v1.w;
  #pragma unroll
  for (int off = 1; off < 8; off <<= 1) {
    sum += __shfl_xor(sum, off);
    sq  += __shfl_xor(sq, off);
  }
  float mean = sum * (1.f / 64.f);
  float var  = sq * (1.f / 64.f) - mean * mean;
  float rstd = rsqrtf(var + LN_EPS);
  int n = n0 + node;
  if (n < N) {
    float4 ga0 = *(const float4*)&gam[fb], ga1 = *(const float4*)&gam[fb + 4];
    float4 be0 = *(const float4*)&bet[fb], be1 = *(const float4*)&bet[fb + 4];
    float4 o0, o1;
    o0.x = (v0.x - mean) * rstd * ga0.x + be0.x;
    o0.y = (v0.y - mean) * rstd * ga0.y + be0.y;
    o0.z = (v0.z - mean) * rstd * ga0.z + be0.z;
    o0.w = (v0.w - mean) * rstd * ga0.w + be0.w;
    o1.x = (v1.x - mean) * rstd * ga1.x + be1.x;
    o1.y = (v1.y - mean) * rstd * ga1.y + be1.y;
    o1.z = (v1.z - mean) * rstd * ga1.z + be1.z;
    o1.w = (v1.w - mean) * rstd * ga1.w + be1.w;
    float* op = &node_emb[(size_t)n * 64 + fb];
    *(float4*)(op + 0) = o0;
    *(float4*)(op + 4) = o1;
  }
}

// ---- graph pooling: batch is sorted; block g segment-sums node_emb[lo:hi) ----
__global__ __launch_bounds__(256) void graph_pool(
    const float* __restrict__ node_emb, const int* __restrict__ batch,
    float* __restrict__ out, int N) {
  __shared__ float red[4][64];
  int g = blockIdx.x;
  int tid = threadIdx.x;
  int j = tid & 63, c = tid >> 6;
  int lo = 0, hi = N;
  while (lo < hi) { int mid = (lo + hi) >> 1; if (batch[mid] < g) lo = mid + 1; else hi = mid; }
  int start = lo;
  lo = 0; hi = N;
  while (lo < hi) { int mid = (lo + hi) >> 1; if (batch[mid] < g + 1) lo = mid + 1; else hi = mid; }
  int end = lo;
  float s = 0.f;
  for (int n = start + c; n < end; n += 4)
    s += node_emb[(size_t)n * 64 + j];
  red[c][j] = s;
  __syncthreads();
  if (c == 0) {
    float tot = red[0][j] + red[1][j] + red[2][j] + red[3][j];
    float inv = 1.f / fmaxf((float)(end - start), 1.f);
    out[g * 64 + j] = tot * inv;
  }
}

extern "C" void kernel_launch(void* const* d_in, const int* in_sizes, int n_in,
                              void* d_out, int out_size, void* d_ws, size_t ws_size,
                              hipStream_t stream) {
  const float* x   = (const float*)d_in[0];
  const float* ef  = (const float*)d_in[1];
  const float* Ws0 = (const float*)d_in[2];
  const float* bs0 = (const float*)d_in[3];
  const float* Wm0 = (const float*)d_in[4];
  const float* bm0 = (const float*)d_in[5];
  const float* g0  = (const float*)d_in[6];
  const float* be0 = (const float*)d_in[7];
  const float* Ws1 = (const float*)d_in[8];
  const float* bs1 = (const float*)d_in[9];
  const float* Wm1 = (const float*)d_in[10];
  const float* bm1 = (const float*)d_in[11];
  const float* g1  = (const float*)d_in[12];
  const float* be1 = (const float*)d_in[13];
  const int* edge_index = (const int*)d_in[14];
  const int* batch = (const int*)d_in[15];

  const int N = in_sizes[0] / 128;
  const int E = in_sizes[14] / 2;
  const int G = 64;
  const int* src = edge_index;
  const int* tgt = edge_index + E;

  char* ws = (char*)d_ws;
  size_t off = 0;
  auto alloc = [&](size_t bytes) -> void* {
    void* p = ws + off;
    off = (off + bytes + 255) & ~(size_t)255;
    return p;
  };
  float* SX     = (float*)alloc((size_t)N * 128 * 4);  // reused as SH for layer 1
  float* SE     = (float*)alloc((size_t)N * 16 * 4);
  float* deg    = (float*)alloc((size_t)N * 4);
  float* h      = (float*)alloc((size_t)N * 128 * 4);
  int*   cnt    = (int*)alloc((size_t)N * 4);          // reused as cursor for fill
  int*   rowptr = (int*)alloc((size_t)(N + 1) * 4);
  int2*  csr    = (int2*)alloc((size_t)E * 8);

  hipMemsetAsync(cnt, 0, (size_t)N * 4, stream);

  hist_tgt<<<(E + 255) / 256, 256, 0, stream>>>(tgt, cnt, E);
  scan_rowptr<<<1, 1024, 0, stream>>>(cnt, rowptr, N);
  hipMemsetAsync(cnt, 0, (size_t)N * 4, stream);  // reuse as fill cursor
  fill_csr<<<(E + 255) / 256, 256, 0, stream>>>(src, tgt, rowptr, cnt, csr, E);

  agg0<<<(N + 3) / 4, 256, 0, stream>>>(x, ef, rowptr, csr, SX, SE, deg, N);

  layer0_gemm<<<(N + 31) / 32, 256, 0, stream>>>(
      x, SX, SE, deg, Ws0, Wm0, bs0, bm0, g0, be0, h, N);

  agg1<<<(N + 3) / 4, 256, 0, stream>>>(h, rowptr, csr, SX, N);

  layer1_gemm<<<(N + 31) / 32, 256, 0, stream>>>(
      h, SX, SE, deg, Ws1, Wm1, bs1, bm1, g1, be1, (float*)d_out, N);

  graph_pool<<<G, 256, 0, stream>>>((const float*)d_out, batch,
                                    (float*)d_out + (size_t)N * 64, N);
}

// Round 9
// 602.034 us; speedup vs baseline: 6.2305x; 1.0317x over previous
//
#include <hip/hip_runtime.h>

#define LN_EPS 1e-5f
#define UPAD 292   // u row stride (floats)

// ---- CSR build: histogram of tgt ----
__global__ __launch_bounds__(256) void hist_tgt(
    const int* __restrict__ tgt, int* __restrict__ cnt, int E) {
  int e = blockIdx.x * 256 + threadIdx.x;
  if (e < E) atomicAdd(&cnt[tgt[e]], 1);
}

// ---- CSR build: exclusive scan over cnt -> rowptr (single block) ----
__global__ __launch_bounds__(1024) void scan_rowptr(
    const int* __restrict__ cnt, int* __restrict__ rowptr, int N) {
  __shared__ int part[1024];
  int tid = threadIdx.x;
  int per = (N + 1023) / 1024;
  int start = tid * per;
  int end = min(start + per, N);
  int s = 0;
  for (int i = start; i < end; ++i) s += cnt[i];
  part[tid] = s;
  __syncthreads();
  for (int off = 1; off < 1024; off <<= 1) {
    int v = (tid >= off) ? part[tid - off] : 0;
    __syncthreads();
    part[tid] += v;
    __syncthreads();
  }
  int excl = (tid == 0) ? 0 : part[tid - 1];
  for (int i = start; i < end; ++i) {
    rowptr[i] = excl;
    excl += cnt[i];
  }
  if (tid == 1023) rowptr[N] = excl;
}

// ---- CSR build: fill (src, eid) pairs ----
__global__ __launch_bounds__(256) void fill_csr(
    const int* __restrict__ src, const int* __restrict__ tgt,
    const int* __restrict__ rowptr, int* __restrict__ cur,
    int2* __restrict__ csr, int E) {
  int e = blockIdx.x * 256 + threadIdx.x;
  if (e >= E) return;
  int t = tgt[e];
  int pos = atomicAdd(&cur[t], 1);
  csr[rowptr[t] + pos] = make_int2(src[e], e);
}

// ---- gather-aggregate layer 0: one wave per node, float4/lane, 2 edges per
// wave-instruction (lane<32 even edge, lane>=32 odd edge), 4-pair unroll ----
__global__ __launch_bounds__(256) void agg0(
    const float* __restrict__ x, const float* __restrict__ ef,
    const int* __restrict__ rowptr, const int2* __restrict__ csr,
    float* __restrict__ SX, float* __restrict__ SE,
    float* __restrict__ degF, int N) {
  int n = blockIdx.x * 4 + (threadIdx.x >> 6);
  if (n >= N) return;
  int lane = threadIdx.x & 63;
  int half = lane >> 5;        // 0: even edges, 1: odd edges
  int fg = lane & 31;          // feature group
  int fl = fg * 4;             // float4 offset into 128-wide row
  bool efl = fg < 4;           // lanes covering the 16-wide ef row
  int b = rowptr[n], e = rowptr[n + 1];
  int d = e - b;
  float4 acc  = make_float4(0.f, 0.f, 0.f, 0.f);
  float4 acce = make_float4(0.f, 0.f, 0.f, 0.f);
  int pairs = d >> 1;
  int i = b + half;
  int t = 0;
  for (; t + 4 <= pairs; t += 4, i += 8) {
    int2 p0 = csr[i], p1 = csr[i + 2], p2 = csr[i + 4], p3 = csr[i + 6];
    float4 v0 = *(const float4*)&x[(size_t)p0.x * 128 + fl];
    float4 v1 = *(const float4*)&x[(size_t)p1.x * 128 + fl];
    float4 v2 = *(const float4*)&x[(size_t)p2.x * 128 + fl];
    float4 v3 = *(const float4*)&x[(size_t)p3.x * 128 + fl];
    acc.x += (v0.x + v1.x) + (v2.x + v3.x);
    acc.y += (v0.y + v1.y) + (v2.y + v3.y);
    acc.z += (v0.z + v1.z) + (v2.z + v3.z);
    acc.w += (v0.w + v1.w) + (v2.w + v3.w);
    if (efl) {
      float4 e0 = *(const float4*)&ef[(size_t)p0.y * 16 + fl];
      float4 e1 = *(const float4*)&ef[(size_t)p1.y * 16 + fl];
      float4 e2 = *(const float4*)&ef[(size_t)p2.y * 16 + fl];
      float4 e3 = *(const float4*)&ef[(size_t)p3.y * 16 + fl];
      acce.x += (e0.x + e1.x) + (e2.x + e3.x);
      acce.y += (e0.y + e1.y) + (e2.y + e3.y);
      acce.z += (e0.z + e1.z) + (e2.z + e3.z);
      acce.w += (e0.w + e1.w) + (e2.w + e3.w);
    }
  }
  for (; t < pairs; ++t, i += 2) {
    int2 p = csr[i];
    float4 v = *(const float4*)&x[(size_t)p.x * 128 + fl];
    acc.x += v.x; acc.y += v.y; acc.z += v.z; acc.w += v.w;
    if (efl) {
      float4 ev = *(const float4*)&ef[(size_t)p.y * 16 + fl];
      acce.x += ev.x; acce.y += ev.y; acce.z += ev.z; acce.w += ev.w;
    }
  }
  if ((d & 1) && half == 0) {
    int2 p = csr[e - 1];
    float4 v = *(const float4*)&x[(size_t)p.x * 128 + fl];
    acc.x += v.x; acc.y += v.y; acc.z += v.z; acc.w += v.w;
    if (efl) {
      float4 ev = *(const float4*)&ef[(size_t)p.y * 16 + fl];
      acce.x += ev.x; acce.y += ev.y; acce.z += ev.z; acce.w += ev.w;
    }
  }
  // combine even/odd halves
  acc.x += __shfl_xor(acc.x, 32);
  acc.y += __shfl_xor(acc.y, 32);
  acc.z += __shfl_xor(acc.z, 32);
  acc.w += __shfl_xor(acc.w, 32);
  acce.x += __shfl_xor(acce.x, 32);
  acce.y += __shfl_xor(acce.y, 32);
  acce.z += __shfl_xor(acce.z, 32);
  acce.w += __shfl_xor(acce.w, 32);
  if (half == 0) {
    *(float4*)&SX[(size_t)n * 128 + fl] = acc;
    if (efl) *(float4*)&SE[(size_t)n * 16 + fl] = acce;
    if (lane == 0) degF[n] = (float)d;
  }
}

// ---- gather-aggregate layer 1: SH[n] = sum h[src], same paired-row scheme ----
__global__ __launch_bounds__(256) void agg1(
    const float* __restrict__ h, const int* __restrict__ rowptr,
    const int2* __restrict__ csr, float* __restrict__ SH, int N) {
  int n = blockIdx.x * 4 + (threadIdx.x >> 6);
  if (n >= N) return;
  int lane = threadIdx.x & 63;
  int half = lane >> 5;
  int fl = (lane & 31) * 4;
  int b = rowptr[n], e = rowptr[n + 1];
  int d = e - b;
  float4 acc = make_float4(0.f, 0.f, 0.f, 0.f);
  int pairs = d >> 1;
  int i = b + half;
  int t = 0;
  for (; t + 4 <= pairs; t += 4, i += 8) {
    int2 p0 = csr[i], p1 = csr[i + 2], p2 = csr[i + 4], p3 = csr[i + 6];
    float4 v0 = *(const float4*)&h[(size_t)p0.x * 128 + fl];
    float4 v1 = *(const float4*)&h[(size_t)p1.x * 128 + fl];
    float4 v2 = *(const float4*)&h[(size_t)p2.x * 128 + fl];
    float4 v3 = *(const float4*)&h[(size_t)p3.x * 128 + fl];
    acc.x += (v0.x + v1.x) + (v2.x + v3.x);
    acc.y += (v0.y + v1.y) + (v2.y + v3.y);
    acc.z += (v0.z + v1.z) + (v2.z + v3.z);
    acc.w += (v0.w + v1.w) + (v2.w + v3.w);
  }
  for (; t < pairs; ++t, i += 2) {
    int2 p = csr[i];
    float4 v = *(const float4*)&h[(size_t)p.x * 128 + fl];
    acc.x += v.x; acc.y += v.y; acc.z += v.z; acc.w += v.w;
  }
  if ((d & 1) && half == 0) {
    int2 p = csr[e - 1];
    float4 v = *(const float4*)&h[(size_t)p.x * 128 + fl];
    acc.x += v.x; acc.y += v.y; acc.z += v.z; acc.w += v.w;
  }
  acc.x += __shfl_xor(acc.x, 32);
  acc.y += __shfl_xor(acc.y, 32);
  acc.z += __shfl_xor(acc.z, 32);
  acc.w += __shfl_xor(acc.w, 32);
  if (half == 0)
    *(float4*)&SH[(size_t)n * 128 + fl] = acc;
}

// ---- layer 0 GEMM: [32 nodes x 272] @ [272 x 128] + bias + LN + ReLU ----
// No weight LDS staging: weights read direct from global (L1/L2-resident),
// barrier-free K-loop, 4 blocks/CU.
__global__ __launch_bounds__(256, 4) void layer0_gemm(
    const float* __restrict__ x, const float* __restrict__ SX,
    const float* __restrict__ SE, const float* __restrict__ deg,
    const float* __restrict__ Ws, const float* __restrict__ Wm,
    const float* __restrict__ bs, const float* __restrict__ bm,
    const float* __restrict__ gam, const float* __restrict__ bet,
    float* __restrict__ h, int N) {
  __shared__ float u[32][UPAD];
  __shared__ float dgs[32], dinv[32];
  int tid = threadIdx.x;
  int n0 = blockIdx.x * 32;
  if (tid < 32) {
    int n = n0 + tid;
    float dg = (n < N) ? deg[n] : 0.f;
    dgs[tid] = dg;
    dinv[tid] = dg > 0.f ? 1.f / dg : 0.f;
  }
  __syncthreads();
  // stage u: x | SX/deg | SE/deg (float4 vectorized)
  for (int idx = tid; idx < 1024; idx += 256) {
    int m = idx >> 5, f = (idx & 31) * 4;
    int n = n0 + m;
    float4 xv = make_float4(0.f, 0.f, 0.f, 0.f), sv = xv;
    if (n < N) {
      xv = *(const float4*)&x[(size_t)n * 128 + f];
      sv = *(const float4*)&SX[(size_t)n * 128 + f];
      float di = dinv[m];
      sv.x *= di; sv.y *= di; sv.z *= di; sv.w *= di;
    }
    *(float4*)&u[m][f] = xv;
    *(float4*)&u[m][128 + f] = sv;
  }
  if (tid < 128) {
    int m = tid >> 2, f = (tid & 3) * 4;
    int n = n0 + m;
    float4 ev = make_float4(0.f, 0.f, 0.f, 0.f);
    if (n < N) {
      ev = *(const float4*)&SE[(size_t)n * 16 + f];
      float di = dinv[m];
      ev.x *= di; ev.y *= di; ev.z *= di; ev.w *= di;
    }
    *(float4*)&u[m][256 + f] = ev;
  }
  __syncthreads();

  int tn = tid >> 5, tj = tid & 31;
  int jb = tj * 4;
  float4 bsv = *(const float4*)&bs[jb];
  float4 bmv = *(const float4*)&bm[jb];
  float acc[4][4];
  #pragma unroll
  for (int m = 0; m < 4; ++m) {
    bool has = dgs[tn * 4 + m] > 0.f;
    acc[m][0] = bsv.x + (has ? bmv.x : 0.f);
    acc[m][1] = bsv.y + (has ? bmv.y : 0.f);
    acc[m][2] = bsv.z + (has ? bmv.z : 0.f);
    acc[m][3] = bsv.w + (has ? bmv.w : 0.f);
  }

  // k-loop part 1: Ws over u[:,0:128]
  #pragma unroll 2
  for (int k = 0; k < 128; k += 4) {
    float4 wv[4], uv[4];
    #pragma unroll
    for (int t = 0; t < 4; ++t) wv[t] = *(const float4*)&Ws[(size_t)(k + t) * 128 + jb];
    #pragma unroll
    for (int m = 0; m < 4; ++m) uv[m] = *(const float4*)&u[tn * 4 + m][k];
    #pragma unroll
    for (int m = 0; m < 4; ++m) {
      float us[4] = {uv[m].x, uv[m].y, uv[m].z, uv[m].w};
      #pragma unroll
      for (int t = 0; t < 4; ++t) {
        acc[m][0] = fmaf(us[t], wv[t].x, acc[m][0]);
        acc[m][1] = fmaf(us[t], wv[t].y, acc[m][1]);
        acc[m][2] = fmaf(us[t], wv[t].z, acc[m][2]);
        acc[m][3] = fmaf(us[t], wv[t].w, acc[m][3]);
      }
    }
  }
  // k-loop part 2: Wm over u[:,128:272]
  #pragma unroll 2
  for (int k = 0; k < 144; k += 4) {
    float4 wv[4], uv[4];
    #pragma unroll
    for (int t = 0; t < 4; ++t) wv[t] = *(const float4*)&Wm[(size_t)(k + t) * 128 + jb];
    #pragma unroll
    for (int m = 0; m < 4; ++m) uv[m] = *(const float4*)&u[tn * 4 + m][128 + k];
    #pragma unroll
    for (int m = 0; m < 4; ++m) {
      float us[4] = {uv[m].x, uv[m].y, uv[m].z, uv[m].w};
      #pragma unroll
      for (int t = 0; t < 4; ++t) {
        acc[m][0] = fmaf(us[t], wv[t].x, acc[m][0]);
        acc[m][1] = fmaf(us[t], wv[t].y, acc[m][1]);
        acc[m][2] = fmaf(us[t], wv[t].z, acc[m][2]);
        acc[m][3] = fmaf(us[t], wv[t].w, acc[m][3]);
      }
    }
  }

  __syncthreads();
  #pragma unroll
  for (int m = 0; m < 4; ++m)
    *(float4*)&u[tn * 4 + m][jb] = make_float4(acc[m][0], acc[m][1], acc[m][2], acc[m][3]);
  __syncthreads();

  int node = tid >> 3, s = tid & 7;
  int fb = s * 16;
  float4 v0 = *(const float4*)&u[node][fb];
  float4 v1 = *(const float4*)&u[node][fb + 4];
  float4 v2 = *(const float4*)&u[node][fb + 8];
  float4 v3 = *(const float4*)&u[node][fb + 12];
  float sum = v0.x + v0.y + v0.z + v0.w + v1.x + v1.y + v1.z + v1.w
            + v2.x + v2.y + v2.z + v2.w + v3.x + v3.y + v3.z + v3.w;
  float sq  = v0.x*v0.x + v0.y*v0.y + v0.z*v0.z + v0.w*v0.w
            + v1.x*v1.x + v1.y*v1.y + v1.z*v1.z + v1.w*v1.w
            + v2.x*v2.x + v2.y*v2.y + v2.z*v2.z + v2.w*v2.w
            + v3.x*v3.x + v3.y*v3.y + v3.z*v3.z + v3.w*v3.w;
  #pragma unroll
  for (int off = 1; off < 8; off <<= 1) {
    sum += __shfl_xor(sum, off);
    sq  += __shfl_xor(sq, off);
  }
  float mean = sum * (1.f / 128.f);
  float var  = sq * (1.f / 128.f) - mean * mean;
  float rstd = rsqrtf(var + LN_EPS);
  int n = n0 + node;
  if (n < N) {
    float4 ga0 = *(const float4*)&gam[fb],     ga1 = *(const float4*)&gam[fb + 4];
    float4 ga2 = *(const float4*)&gam[fb + 8], ga3 = *(const float4*)&gam[fb + 12];
    float4 be0 = *(const float4*)&bet[fb],     be1 = *(const float4*)&bet[fb + 4];
    float4 be2 = *(const float4*)&bet[fb + 8], be3 = *(const float4*)&bet[fb + 12];
    float* hp = &h[(size_t)n * 128 + fb];
    float4 o;
    o.x = fmaxf((v0.x - mean) * rstd * ga0.x + be0.x, 0.f);
    o.y = fmaxf((v0.y - mean) * rstd * ga0.y + be0.y, 0.f);
    o.z = fmaxf((v0.z - mean) * rstd * ga0.z + be0.z, 0.f);
    o.w = fmaxf((v0.w - mean) * rstd * ga0.w + be0.w, 0.f);
    *(float4*)(hp + 0) = o;
    o.x = fmaxf((v1.x - mean) * rstd * ga1.x + be1.x, 0.f);
    o.y = fmaxf((v1.y - mean) * rstd * ga1.y + be1.y, 0.f);
    o.z = fmaxf((v1.z - mean) * rstd * ga1.z + be1.z, 0.f);
    o.w = fmaxf((v1.w - mean) * rstd * ga1.w + be1.w, 0.f);
    *(float4*)(hp + 4) = o;
    o.x = fmaxf((v2.x - mean) * rstd * ga2.x + be2.x, 0.f);
    o.y = fmaxf((v2.y - mean) * rstd * ga2.y + be2.y, 0.f);
    o.z = fmaxf((v2.z - mean) * rstd * ga2.z + be2.z, 0.f);
    o.w = fmaxf((v2.w - mean) * rstd * ga2.w + be2.w, 0.f);
    *(float4*)(hp + 8) = o;
    o.x = fmaxf((v3.x - mean) * rstd * ga3.x + be3.x, 0.f);
    o.y = fmaxf((v3.y - mean) * rstd * ga3.y + be3.y, 0.f);
    o.z = fmaxf((v3.z - mean) * rstd * ga3.z + be3.z, 0.f);
    o.w = fmaxf((v3.w - mean) * rstd * ga3.w + be3.w, 0.f);
    *(float4*)(hp + 12) = o;
  }
}

// ---- layer 1 GEMM: [32 nodes x 272] @ [272 x 64] + bias + LN (no atomics) ----
__global__ __launch_bounds__(256, 4) void layer1_gemm(
    const float* __restrict__ hin, const float* __restrict__ SH,
    const float* __restrict__ SE, const float* __restrict__ deg,
    const float* __restrict__ Ws, const float* __restrict__ Wm,
    const float* __restrict__ bs, const float* __restrict__ bm,
    const float* __restrict__ gam, const float* __restrict__ bet,
    float* __restrict__ node_emb, int N) {
  __shared__ float u[32][UPAD];
  __shared__ float dgs[32], dinv[32];
  int tid = threadIdx.x;
  int n0 = blockIdx.x * 32;
  if (tid < 32) {
    int n = n0 + tid;
    float dg = (n < N) ? deg[n] : 0.f;
    dgs[tid] = dg;
    dinv[tid] = dg > 0.f ? 1.f / dg : 0.f;
  }
  __syncthreads();
  for (int idx = tid; idx < 1024; idx += 256) {
    int m = idx >> 5, f = (idx & 31) * 4;
    int n = n0 + m;
    float4 xv = make_float4(0.f, 0.f, 0.f, 0.f), sv = xv;
    if (n < N) {
      xv = *(const float4*)&hin[(size_t)n * 128 + f];
      sv = *(const float4*)&SH[(size_t)n * 128 + f];
      float di = dinv[m];
      sv.x *= di; sv.y *= di; sv.z *= di; sv.w *= di;
    }
    *(float4*)&u[m][f] = xv;
    *(float4*)&u[m][128 + f] = sv;
  }
  if (tid < 128) {
    int m = tid >> 2, f = (tid & 3) * 4;
    int n = n0 + m;
    float4 ev = make_float4(0.f, 0.f, 0.f, 0.f);
    if (n < N) {
      ev = *(const float4*)&SE[(size_t)n * 16 + f];
      float di = dinv[m];
      ev.x *= di; ev.y *= di; ev.z *= di; ev.w *= di;
    }
    *(float4*)&u[m][256 + f] = ev;
  }
  __syncthreads();

  int tn = tid >> 5, tj = tid & 31;
  int jb = tj * 2;
  float2 bsv = *(const float2*)&bs[jb];
  float2 bmv = *(const float2*)&bm[jb];
  float acc[4][2];
  #pragma unroll
  for (int m = 0; m < 4; ++m) {
    bool has = dgs[tn * 4 + m] > 0.f;
    acc[m][0] = bsv.x + (has ? bmv.x : 0.f);
    acc[m][1] = bsv.y + (has ? bmv.y : 0.f);
  }

  #pragma unroll 2
  for (int k = 0; k < 128; k += 4) {
    float2 wv[4];
    float4 uv[4];
    #pragma unroll
    for (int t = 0; t < 4; ++t) wv[t] = *(const float2*)&Ws[(size_t)(k + t) * 64 + jb];
    #pragma unroll
    for (int m = 0; m < 4; ++m) uv[m] = *(const float4*)&u[tn * 4 + m][k];
    #pragma unroll
    for (int m = 0; m < 4; ++m) {
      float us[4] = {uv[m].x, uv[m].y, uv[m].z, uv[m].w};
      #pragma unroll
      for (int t = 0; t < 4; ++t) {
        acc[m][0] = fmaf(us[t], wv[t].x, acc[m][0]);
        acc[m][1] = fmaf(us[t], wv[t].y, acc[m][1]);
      }
    }
  }
  #pragma unroll 2
  for (int k = 0; k < 144; k += 4) {
    float2 wv[4];
    float4 uv[4];
    #pragma unroll
    for (int t = 0; t < 4; ++t) wv[t] = *(const float2*)&Wm[(size_t)(k + t) * 64 + jb];
    #pragma unroll
    for (int m = 0; m < 4; ++m) uv[m] = *(const float4*)&u[tn * 4 + m][128 + k];
    #pragma unroll
    for (int m = 0; m < 4; ++m) {
      float us[4] = {uv[m].x, uv[m].y, uv[m].z, uv[m].w};
      #pragma unroll
      for (int t = 0; t < 4; ++t) {
        acc[m][0] = fmaf(us[t], wv[t].x, acc[m][0]);
        acc[m][1] = fmaf(us[t], wv[t].y, acc[m][1]);
      }
    }
  }

  __syncthreads();
  #pragma unroll
  for (int m = 0; m < 4; ++m)
    *(float2*)&u[tn * 4 + m][jb] = make_float2(acc[m][0], acc[m][1]);
  __syncthreads();

  int node = tid >> 3, s = tid & 7;
  int fb = s * 8;
  float4 v0 = *(const float4*)&u[node][fb];
  float4 v1 = *(const float4*)&u[node][fb + 4];
  float sum = v0.x + v0.y + v0.z + v0.w + v1.x + v1.y + v1.z + v1.w;
  float sq  = v0.x*v0.x + v0.y*v0.y + v0.z*v0.z + v0.w*v0.w
            + v1.x*v1.x + v1.y*v1.y + v1.z*v1.z + v1.w*v1.w;
  #pragma unroll
  for (int off = 1; off < 8; off <<= 1) {
    sum += __shfl_xor(sum, off);
    sq  += __shfl_xor(sq, off);
  }
  float mean = sum * (1.f / 64.f);
  float var  = sq * (1.f / 64.f) - mean * mean;
  float rstd = rsqrtf(var + LN_EPS);
  int n = n0 + node;
  if (n < N) {
    float4 ga0 = *(const float4*)&gam[fb], ga1 = *(const float4*)&gam[fb + 4];
    float4 be0 = *(const float4*)&bet[fb], be1 = *(const float4*)&bet[fb + 4];
    float4 o0, o1;
    o0.x = (v0.x - mean) * rstd * ga0.x + be0.x;
    o0.y = (v0.y - mean) * rstd * ga0.y + be0.y;
    o0.z = (v0.z - mean) * rstd * ga0.z + be0.z;
    o0.w = (v0.w - mean) * rstd * ga0.w + be0.w;
    o1.x = (v1.x - mean) * rstd * ga1.x + be1.x;
    o1.y = (v1.y - mean) * rstd * ga1.y + be1.y;
    o1.z = (v1.z - mean) * rstd * ga1.z + be1.z;
    o1.w = (v1.w - mean) * rstd * ga1.w + be1.w;
    float* op = &node_emb[(size_t)n * 64 + fb];
    *(float4*)(op + 0) = o0;
    *(float4*)(op + 4) = o1;
  }
}

// ---- graph pooling: batch is sorted; block g segment-sums node_emb[lo:hi) ----
__global__ __launch_bounds__(256) void graph_pool(
    const float* __restrict__ node_emb, const int* __restrict__ batch,
    float* __restrict__ out, int N) {
  __shared__ float red[4][64];
  int g = blockIdx.x;
  int tid = threadIdx.x;
  int j = tid & 63, c = tid >> 6;
  int lo = 0, hi = N;
  while (lo < hi) { int mid = (lo + hi) >> 1; if (batch[mid] < g) lo = mid + 1; else hi = mid; }
  int start = lo;
  lo = 0; hi = N;
  while (lo < hi) { int mid = (lo + hi) >> 1; if (batch[mid] < g + 1) lo = mid + 1; else hi = mid; }
  int end = lo;
  float s = 0.f;
  for (int n = start + c; n < end; n += 4)
    s += node_emb[(size_t)n * 64 + j];
  red[c][j] = s;
  __syncthreads();
  if (c == 0) {
    float tot = red[0][j] + red[1][j] + red[2][j] + red[3][j];
    float inv = 1.f / fmaxf((float)(end - start), 1.f);
    out[g * 64 + j] = tot * inv;
  }
}

extern "C" void kernel_launch(void* const* d_in, const int* in_sizes, int n_in,
                              void* d_out, int out_size, void* d_ws, size_t ws_size,
                              hipStream_t stream) {
  const float* x   = (const float*)d_in[0];
  const float* ef  = (const float*)d_in[1];
  const float* Ws0 = (const float*)d_in[2];
  const float* bs0 = (const float*)d_in[3];
  const float* Wm0 = (const float*)d_in[4];
  const float* bm0 = (const float*)d_in[5];
  const float* g0  = (const float*)d_in[6];
  const float* be0 = (const float*)d_in[7];
  const float* Ws1 = (const float*)d_in[8];
  const float* bs1 = (const float*)d_in[9];
  const float* Wm1 = (const float*)d_in[10];
  const float* bm1 = (const float*)d_in[11];
  const float* g1  = (const float*)d_in[12];
  const float* be1 = (const float*)d_in[13];
  const int* edge_index = (const int*)d_in[14];
  const int* batch = (const int*)d_in[15];

  const int N = in_sizes[0] / 128;
  const int E = in_sizes[14] / 2;
  const int G = 64;
  const int* src = edge_index;
  const int* tgt = edge_index + E;

  char* ws = (char*)d_ws;
  size_t off = 0;
  auto alloc = [&](size_t bytes) -> void* {
    void* p = ws + off;
    off = (off + bytes + 255) & ~(size_t)255;
    return p;
  };
  float* SX     = (float*)alloc((size_t)N * 128 * 4);  // reused as SH for layer 1
  float* SE     = (float*)alloc((size_t)N * 16 * 4);
  float* deg    = (float*)alloc((size_t)N * 4);
  float* h      = (float*)alloc((size_t)N * 128 * 4);
  int*   cnt    = (int*)alloc((size_t)N * 4);          // reused as cursor for fill
  int*   rowptr = (int*)alloc((size_t)(N + 1) * 4);
  int2*  csr    = (int2*)alloc((size_t)E * 8);

  hipMemsetAsync(cnt, 0, (size_t)N * 4, stream);

  hist_tgt<<<(E + 255) / 256, 256, 0, stream>>>(tgt, cnt, E);
  scan_rowptr<<<1, 1024, 0, stream>>>(cnt, rowptr, N);
  hipMemsetAsync(cnt, 0, (size_t)N * 4, stream);  // reuse as fill cursor
  fill_csr<<<(E + 255) / 256, 256, 0, stream>>>(src, tgt, rowptr, cnt, csr, E);

  agg0<<<(N + 3) / 4, 256, 0, stream>>>(x, ef, rowptr, csr, SX, SE, deg, N);

  layer0_gemm<<<(N + 31) / 32, 256, 0, stream>>>(
      x, SX, SE, deg, Ws0, Wm0, bs0, bm0, g0, be0, h, N);

  agg1<<<(N + 3) / 4, 256, 0, stream>>>(h, rowptr, csr, SX, N);

  layer1_gemm<<<(N + 31) / 32, 256, 0, stream>>>(
      h, SX, SE, deg, Ws1, Wm1, bs1, bm1, g1, be1, (float*)d_out, N);

  graph_pool<<<G, 256, 0, stream>>>((const float*)d_out, batch,
                                    (float*)d_out + (size_t)N * 64, N);
}